// Round 7
// baseline (407.007 us; speedup 1.0000x reference)
//
#include <hip/hip_runtime.h>
#include <hip/hip_bf16.h>

// MultiHeadAttention B=2,S=2048,D=768,H=12,Dk=64. fp32 in, fp32 out (proven R4).
// FAST: [to_bf16] -> [qkv2: BK=64 gl_lds GEMM; Q scaled by 0.125*log2e in epilogue;
// V stored transposed+pos32-permuted] -> [attn3: wave=64q x 32keys, exp2-only
// softmax (no max/clamp), l via ones-MFMA, 4-wave merge] -> [bt2 fp32 out].
// FALLBACK (small ws): round-4 proven pipeline.
// Verified MFMA 16x16x32 layouts: A[m=l15][k=quad*8+j], B[n=l15][k=quad*8+j],
// C/D col=l15 row=quad*4+reg.
// xor-swizzle: LDS slot (row,c8) holds global chunk (c8^(row&7)) [K/A/B] or
// (c16^(d&15)) [V] -> conflict-free b128 reads with lane-linear gl_lds dst.

typedef __bf16 bf16x8 __attribute__((ext_vector_type(8)));
typedef float f32x4 __attribute__((ext_vector_type(4)));
typedef unsigned short u16;
typedef unsigned int u32;
typedef u16 u16x8 __attribute__((ext_vector_type(8)));
typedef u16 u16x4 __attribute__((ext_vector_type(4)));

#define SEQ 2048
#define DM  768
#define NH  12
#define DK  64
#define NBH 24
#define MTOT 4096
#define NEL 3145728   // MTOT*DM
#define NWL 589824    // DM*DM
#define QSCALE 0.18033688f   // 0.125 * log2(e): scores pre-scaled for exp2

__device__ __forceinline__ u16 f2b(float v) {
  __bf16 t = (__bf16)v;
  return __builtin_bit_cast(u16, t);
}

__device__ __forceinline__ void gl_lds16(const u16* g, u16* l) {
  __builtin_amdgcn_global_load_lds(
      (const __attribute__((address_space(1))) void*)g,
      (__attribute__((address_space(3))) void*)l, 16, 0, 0);
}

// key permutation within 32-groups so P's MFMA B-frag register order (k=quad*8+j)
// matches V's stored column order: pos32(MT*16+quad*4+r) = quad*8 + MT*4 + r.
__device__ __forceinline__ int pos32(int k) {
  return (k < 16) ? (((k >> 2) << 3) + (k & 3))
                  : ((((k & 15) >> 2) << 3) + (k & 3) + 4);
}

// ---------------- FAST PATH ----------------

__global__ __launch_bounds__(256) void to_bf16(
    const float* __restrict__ s0, const float* __restrict__ s1, const float* __restrict__ s2,
    const float* __restrict__ s3, const float* __restrict__ s4, const float* __restrict__ s5,
    const float* __restrict__ s6, u16* __restrict__ Xb, u16* __restrict__ Wb)
{
  size_t c = (size_t)blockIdx.x * 256 + threadIdx.x;
  const float* src;
  u16* dst;
  if (c < 1179648) {
    int seg = (int)(c / 393216);
    size_t off = (c % 393216) * 8;
    src = (seg == 0 ? s0 : seg == 1 ? s1 : s2) + off;
    dst = Xb + (size_t)seg * NEL + off;
  } else {
    size_t c2 = c - 1179648;
    int seg = (int)(c2 / 73728);
    size_t off = (c2 % 73728) * 8;
    src = (seg == 0 ? s3 : seg == 1 ? s4 : seg == 2 ? s5 : s6) + off;
    dst = Wb + (size_t)seg * NWL + off;
  }
  float4 f0 = *(const float4*)(src);
  float4 f1 = *(const float4*)(src + 4);
  u16x8 o;
  o[0] = f2b(f0.x); o[1] = f2b(f0.y); o[2] = f2b(f0.z); o[3] = f2b(f0.w);
  o[4] = f2b(f1.x); o[5] = f2b(f1.y); o[6] = f2b(f1.z); o[7] = f2b(f1.w);
  *(u16x8*)dst = o;
}

// 128x128 tile GEMM, BK=64, gl_lds + xor swizzle. modes: 0 head-major bf16
// (scaled) via LDS-transpose; 1 Vt (d-major, pos32 s); 2 fp32 row-major.
__device__ __forceinline__ void gemm2_core(
    const u16* __restrict__ X, const u16* __restrict__ W, void* __restrict__ Y,
    int m0, int n0, int mode, float scale, u16* As, u16* Bs)
{
  const int tid  = threadIdx.x;
  const int lane = tid & 63, w = tid >> 6;
  const int l15  = lane & 15, quad = lane >> 4;
  const int wm   = (w & 1) * 64, wn = (w >> 1) * 64;

  f32x4 acc[4][4] = {};

  for (int k0 = 0; k0 < DM; k0 += 64) {
    __syncthreads();
#pragma unroll
    for (int i = 0; i < 4; i++) {
      int c = (w * 4 + i) * 64 + lane;
      int row = c >> 3, c8 = c & 7;
      int g8 = c8 ^ (row & 7);
      gl_lds16(X + (size_t)(m0 + row) * DM + k0 + g8 * 8, As + c * 8);
      gl_lds16(W + (size_t)(n0 + row) * DM + k0 + g8 * 8, Bs + c * 8);
    }
    __syncthreads();
#pragma unroll
    for (int dk = 0; dk < 2; dk++) {
      bf16x8 af[4], bf[4];
      int ph = ((dk * 4 + quad) ^ (l15 & 7)) * 8;
#pragma unroll
      for (int t = 0; t < 4; t++) {
        af[t] = *(const bf16x8*)(&As[(wm + t * 16 + l15) * 64 + ph]);
        bf[t] = *(const bf16x8*)(&Bs[(wn + t * 16 + l15) * 64 + ph]);
      }
#pragma unroll
      for (int mt = 0; mt < 4; mt++)
#pragma unroll
        for (int nt = 0; nt < 4; nt++)
          acc[mt][nt] = __builtin_amdgcn_mfma_f32_16x16x32_bf16(af[mt], bf[nt], acc[mt][nt], 0, 0, 0);
    }
  }

  if (mode == 2) {
    float* O = (float*)Y;
#pragma unroll
    for (int mt = 0; mt < 4; mt++) {
      int mg = m0 + wm + mt * 16 + quad * 4;
#pragma unroll
      for (int nt = 0; nt < 4; nt++) {
        int j = n0 + wn + nt * 16 + l15;
#pragma unroll
        for (int r = 0; r < 4; r++)
          O[(size_t)(mg + r) * DM + j] = acc[mt][nt][r];
      }
    }
  } else if (mode == 1) {       // Vt[bh][d][s']
    u16* O = (u16*)Y;
#pragma unroll
    for (int mt = 0; mt < 4; mt++) {
      int mg = m0 + wm + mt * 16 + quad * 4;
      int b = mg >> 11, s = mg & 2047;
      int sp = (s & ~31) | pos32(s & 31);
#pragma unroll
      for (int nt = 0; nt < 4; nt++) {
        int j = n0 + wn + nt * 16 + l15;
        int h = j >> 6, d = j & 63;
        u16x4 o;
#pragma unroll
        for (int r = 0; r < 4; r++) o[r] = f2b(acc[mt][nt][r]);
        *(u16x4*)&O[((size_t)(b * NH + h) * DK + d) * SEQ + sp] = o;
      }
    }
  } else {                      // head-major via LDS transpose, scaled
    u16* O = (u16*)Y;
    u16* T = As;
#pragma unroll
    for (int h2 = 0; h2 < 2; h2++) {
      __syncthreads();
      if ((w & 1) == h2) {
#pragma unroll
        for (int mt = 0; mt < 4; mt++)
#pragma unroll
          for (int nt = 0; nt < 4; nt++)
#pragma unroll
            for (int r = 0; r < 4; r++)
              T[(mt * 16 + quad * 4 + r) * 128 + wn + nt * 16 + l15] = f2b(acc[mt][nt][r] * scale);
      }
      __syncthreads();
#pragma unroll
      for (int i = 0; i < 4; i++) {
        int c = i * 256 + tid;
        int row = c >> 4, ch = c & 15;
        u16x8 val = *(const u16x8*)&T[row * 128 + ch * 8];
        int m = m0 + h2 * 64 + row;
        int j = n0 + ch * 8;
        int hh = j >> 6, d = j & 63;
        int b = m >> 11, s = m & 2047;
        *(u16x8*)&O[((size_t)(b * NH + hh) * SEQ + s) * DK + d] = val;
      }
    }
  }
}

__global__ __launch_bounds__(256) void qkv2(
    const u16* __restrict__ Xb, const u16* __restrict__ Wb,
    u16* __restrict__ Qhm, u16* __restrict__ Khm, u16* __restrict__ Vt)
{
  __shared__ __align__(16) u16 As[128 * 64];
  __shared__ __align__(16) u16 Bs[128 * 64];
  int mat = blockIdx.z;
  const u16* X = Xb + (size_t)mat * NEL;
  const u16* W = Wb + (size_t)mat * NWL;
  void* Y = (mat == 0) ? (void*)Qhm : (mat == 1) ? (void*)Khm : (void*)Vt;
  float scale = (mat == 0) ? QSCALE : 1.0f;
  gemm2_core(X, W, Y, blockIdx.y * 128, blockIdx.x * 128, (mat == 2) ? 1 : 0, scale, As, Bs);
}

__global__ __launch_bounds__(256) void bt2(
    const u16* __restrict__ Ctx, const u16* __restrict__ Wob, float* __restrict__ Y)
{
  __shared__ __align__(16) u16 As[128 * 64];
  __shared__ __align__(16) u16 Bs[128 * 64];
  gemm2_core(Ctx, Wob, Y, blockIdx.y * 128, blockIdx.x * 128, 2, 1.0f, As, Bs);
}

// attn3: grid (32,24), 4 waves. Each wave: ALL 64 q, its own 32-key quarter of
// each 128-key tile. Q pre-scaled by QSCALE -> p = exp2(sc), no max/clamp.
// l via ones-A MFMA. Epilogue: 4-wave partial-O merge (DT-owner), then store.
__global__ __launch_bounds__(256, 3) void attn3(
    const u16* __restrict__ Qh, const u16* __restrict__ Kh,
    const u16* __restrict__ Vt, u16* __restrict__ ctx)
{
  __shared__ __align__(16) u16 smem[128 * 64 + 64 * 128];  // 32 KB: Ks | Vs; reused as merge buf
  __shared__ float Lsum[4][64];
  u16* Ks = smem;
  u16* Vs = smem + 128 * 64;

  const int tid  = threadIdx.x;
  const int lane = tid & 63, w = tid >> 6;
  const int l15  = lane & 15, quad = lane >> 4;
  const int qt = blockIdx.x, bh = blockIdx.y;
  const int b = bh / NH, h = bh % NH;

  const u16* Qb = Qh + (size_t)bh * SEQ * DK;
  const u16* Kb = Kh + (size_t)bh * SEQ * DK;
  const u16* Vb = Vt + (size_t)bh * DK * SEQ;
  const int q0 = qt * 64;

  bf16x8 qf[4][2];   // B[n=q][k=d]
#pragma unroll
  for (int QT = 0; QT < 4; QT++)
#pragma unroll
    for (int dk = 0; dk < 2; dk++)
      qf[QT][dk] = *(const bf16x8*)&Qb[(size_t)(q0 + QT * 16 + l15) * DK + dk * 32 + quad * 8];

  bf16x8 onef;
#pragma unroll
  for (int j = 0; j < 8; j++) onef[j] = (__bf16)1.0f;

  f32x4 oacc[4][4] = {};   // [DT][QT]  O^T: col=q, row=d
  f32x4 lacc[4] = {};      // [QT] row-sums of P (all 4 r equal)

  for (int kt = 0; kt < SEQ; kt += 128) {
    __syncthreads();
#pragma unroll
    for (int i = 0; i < 4; i++) {
      int c = (w * 4 + i) * 64 + lane;   // K: 1024 chunks, row=c>>3
      int row = c >> 3, c8 = c & 7;
      gl_lds16(Kb + (size_t)(kt + row) * DK + (c8 ^ (row & 7)) * 8, Ks + c * 8);
    }
#pragma unroll
    for (int i = 0; i < 4; i++) {
      int c = (w * 4 + i) * 64 + lane;   // V: 1024 chunks, d=c>>4
      int d = c >> 4, c16 = c & 15;
      gl_lds16(Vb + (size_t)d * SEQ + kt + (c16 ^ (d & 15)) * 8, Vs + c * 8);
    }
    __syncthreads();

    // S^T[key][q]: this wave's 32-key quarter, all 64 q
    f32x4 sc[2][4] = {};
#pragma unroll
    for (int MT = 0; MT < 2; MT++) {
      int row = w * 32 + MT * 16 + l15;
#pragma unroll
      for (int dk = 0; dk < 2; dk++) {
        bf16x8 kf = *(const bf16x8*)&Ks[row * 64 + ((dk * 4 + quad) ^ (l15 & 7)) * 8];
#pragma unroll
        for (int QT = 0; QT < 4; QT++)
          sc[MT][QT] = __builtin_amdgcn_mfma_f32_16x16x32_bf16(kf, qf[QT][dk], sc[MT][QT], 0, 0, 0);
      }
    }

    // p = exp2(sc) straight into PV B-frag order; l via ones-MFMA
    bf16x8 pf[4];
#pragma unroll
    for (int QT = 0; QT < 4; QT++) {
#pragma unroll
      for (int j = 0; j < 8; j++)
        pf[QT][j] = (__bf16)__builtin_amdgcn_exp2f(sc[j >> 2][QT][j & 3]);
      lacc[QT] = __builtin_amdgcn_mfma_f32_16x16x32_bf16(onef, pf[QT], lacc[QT], 0, 0, 0);
    }

    // O^T += V^T * P
    int cL = w * 4 + quad;
#pragma unroll
    for (int DT = 0; DT < 4; DT++) {
      int d = DT * 16 + l15;
      bf16x8 vf = *(const bf16x8*)&Vs[d * 128 + (cL ^ (d & 15)) * 8];
#pragma unroll
      for (int QT = 0; QT < 4; QT++)
        oacc[DT][QT] = __builtin_amdgcn_mfma_f32_16x16x32_bf16(vf, pf[QT], oacc[DT][QT], 0, 0, 0);
    }
  }

  __syncthreads();   // tile reads done; smem becomes merge buffer

  if (quad == 0) {
#pragma unroll
    for (int QT = 0; QT < 4; QT++)
      Lsum[w][QT * 16 + l15] = lacc[QT][0];
  }

  // merge partial O across waves: wave w owns DT=w; two rounds of DT pairs.
  // buf region r3 (0..5): [64 q][18 pad] f32 = 4608 B; total 27648 B <= 32 KB.
  float* fb = (float*)smem;
#pragma unroll
  for (int rd = 0; rd < 2; rd++) {
    int p0 = rd * 2, p1 = rd * 2 + 1;
    __syncthreads();
    if (w != p0) {
      int s3 = (w < p0) ? w : w - 1;
#pragma unroll
      for (int QT = 0; QT < 4; QT++)
        *(f32x4*)&fb[(0 * 3 + s3) * 1152 + (QT * 16 + l15) * 18 + quad * 4] = oacc[p0][QT];
    }
    if (w != p1) {
      int s3 = (w < p1) ? w : w - 1;
#pragma unroll
      for (int QT = 0; QT < 4; QT++)
        *(f32x4*)&fb[(1 * 3 + s3) * 1152 + (QT * 16 + l15) * 18 + quad * 4] = oacc[p1][QT];
    }
    __syncthreads();
    if (w == p0) {
#pragma unroll
      for (int s3 = 0; s3 < 3; s3++)
#pragma unroll
        for (int QT = 0; QT < 4; QT++)
          oacc[p0][QT] += *(const f32x4*)&fb[(0 * 3 + s3) * 1152 + (QT * 16 + l15) * 18 + quad * 4];
    }
    if (w == p1) {
#pragma unroll
      for (int s3 = 0; s3 < 3; s3++)
#pragma unroll
        for (int QT = 0; QT < 4; QT++)
          oacc[p1][QT] += *(const f32x4*)&fb[(1 * 3 + s3) * 1152 + (QT * 16 + l15) * 18 + quad * 4];
    }
  }

  // wave w stores its DT=w tile, normalized by total l
#pragma unroll
  for (int QT = 0; QT < 4; QT++) {
    int q = QT * 16 + l15;
    float inv = 1.0f / (Lsum[0][q] + Lsum[1][q] + Lsum[2][q] + Lsum[3][q]);
    u16x4 ov;
#pragma unroll
    for (int r = 0; r < 4; r++)
      ov[r] = f2b(oacc[w][QT][r] * inv);
    *(u16x4*)&ctx[((size_t)(b * SEQ + q0 + q)) * DM + h * DK + w * 16 + quad * 4] = ov;
  }
}

// ---------------- FALLBACK PATH (round-4, proven) ----------------

__device__ __forceinline__ void stage8(u16* dst, const void* src, size_t elemIdx, int isf32) {
  if (isf32) {
    const float* s = (const float*)src + elemIdx;
    float4 f0 = *(const float4*)(s);
    float4 f1 = *(const float4*)(s + 4);
    u16x8 o;
    o[0] = f2b(f0.x); o[1] = f2b(f0.y); o[2] = f2b(f0.z); o[3] = f2b(f0.w);
    o[4] = f2b(f1.x); o[5] = f2b(f1.y); o[6] = f2b(f1.z); o[7] = f2b(f1.w);
    *(u16x8*)dst = o;
  } else {
    *(float4*)dst = *(const float4*)((const u16*)src + elemIdx);
  }
}

__device__ __forceinline__ void gemm_core_fb(
    const void* __restrict__ X, const void* __restrict__ W, void* __restrict__ Y,
    int m0, int n0, int out_mode, u16* As, u16* Bs, int xf32, int wf32)
{
  const int tid  = threadIdx.x;
  const int lane = tid & 63, w = tid >> 6;
  const int l15  = lane & 15, quad = lane >> 4;
  const int wm   = (w & 1) * 64, wn = (w >> 1) * 64;
  f32x4 acc[4][4] = {};
  for (int k0 = 0; k0 < DM; k0 += 32) {
    __syncthreads();
#pragma unroll
    for (int i = 0; i < 2; i++) {
      int c = i * 256 + tid;
      int row = c >> 2, cc = c & 3;
      stage8(&As[c * 8], X, (size_t)(m0 + row) * DM + k0 + cc * 8, xf32);
      stage8(&Bs[c * 8], W, (size_t)(n0 + row) * DM + k0 + cc * 8, wf32);
    }
    __syncthreads();
    bf16x8 af[4], bf[4];
#pragma unroll
    for (int t = 0; t < 4; t++) {
      af[t] = *(const bf16x8*)(&As[(wm + t * 16 + l15) * 32 + quad * 8]);
      bf[t] = *(const bf16x8*)(&Bs[(wn + t * 16 + l15) * 32 + quad * 8]);
    }
#pragma unroll
    for (int mt = 0; mt < 4; mt++)
#pragma unroll
      for (int nt = 0; nt < 4; nt++)
        acc[mt][nt] = __builtin_amdgcn_mfma_f32_16x16x32_bf16(af[mt], bf[nt], acc[mt][nt], 0, 0, 0);
  }
  if (out_mode == 2) {
    float* O = (float*)Y;
#pragma unroll
    for (int mt = 0; mt < 4; mt++) {
      int mg = m0 + wm + mt * 16 + quad * 4;
#pragma unroll
      for (int nt = 0; nt < 4; nt++) {
        int j = n0 + wn + nt * 16 + l15;
#pragma unroll
        for (int r = 0; r < 4; r++)
          O[(size_t)(mg + r) * DM + j] = acc[mt][nt][r];
      }
    }
  } else {
    u16* O = (u16*)Y;
#pragma unroll
    for (int mt = 0; mt < 4; mt++) {
      int mg = m0 + wm + mt * 16 + quad * 4;
#pragma unroll
      for (int nt = 0; nt < 4; nt++) {
        int j = n0 + wn + nt * 16 + l15;
        int h = j >> 6, d = j & 63;
#pragma unroll
        for (int r = 0; r < 4; r++) {
          int m = mg + r;
          int b = m >> 11, s = m & 2047;
          O[((size_t)(b * NH + h) * SEQ + s) * DK + d] = f2b(acc[mt][nt][r]);
        }
      }
    }
  }
}

__global__ __launch_bounds__(256) void fb_qkv_gemm(
    const float* __restrict__ Xq, const float* __restrict__ Xk, const float* __restrict__ Xv,
    const float* __restrict__ Wq, const float* __restrict__ Wk, const float* __restrict__ Wv,
    u16* __restrict__ Yq, u16* __restrict__ Yk, u16* __restrict__ Yv)
{
  __shared__ __align__(16) u16 As[128 * 32];
  __shared__ __align__(16) u16 Bs[128 * 32];
  int mat = blockIdx.z;
  const float* X = (mat == 0) ? Xq : (mat == 1) ? Xk : Xv;
  const float* W = (mat == 0) ? Wq : (mat == 1) ? Wk : Wv;
  u16*         Y = (mat == 0) ? Yq : (mat == 1) ? Yk : Yv;
  gemm_core_fb(X, W, Y, blockIdx.y * 128, blockIdx.x * 128, 0, As, Bs, 1, 1);
}

__global__ __launch_bounds__(256) void fb_gemm_bt(
    const u16* __restrict__ X, const float* __restrict__ W, float* __restrict__ Y)
{
  __shared__ __align__(16) u16 As[128 * 32];
  __shared__ __align__(16) u16 Bs[128 * 32];
  gemm_core_fb(X, W, Y, blockIdx.y * 128, blockIdx.x * 128, 2, As, Bs, 0, 1);
}

__global__ __launch_bounds__(256) void fb_attn(
    const u16* __restrict__ Qh, const u16* __restrict__ Kh,
    const u16* __restrict__ Vh, u16* __restrict__ ctx)
{
  __shared__ __align__(16) u16 Ks[32 * 88];
  __shared__ __align__(16) u16 Vs[64 * 40];
  __shared__ __align__(16) u16 Ps[4][16 * 32];
  const int tid  = threadIdx.x;
  const int lane = tid & 63, w = tid >> 6;
  const int l15  = lane & 15, quad = lane >> 4;
  const int qt = blockIdx.x, bh = blockIdx.y;
  const int b = bh / NH, h = bh % NH;
  const u16* Qb = Qh + (size_t)bh * SEQ * DK;
  const u16* Kb = Kh + (size_t)bh * SEQ * DK;
  const u16* Vb = Vh + (size_t)bh * SEQ * DK;
  const int q0 = qt * 64 + w * 16;
  bf16x8 qf[2];
#pragma unroll
  for (int kk = 0; kk < 2; kk++)
    qf[kk] = *(const bf16x8*)(&Qb[(size_t)(q0 + l15) * DK + kk * 32 + quad * 8]);
  float m_i[4] = {-INFINITY, -INFINITY, -INFINITY, -INFINITY};
  float l_i[4] = {0.f, 0.f, 0.f, 0.f};
  f32x4 acc[4] = {};
  for (int kt = 0; kt < SEQ; kt += 32) {
    __syncthreads();
    {
      int c = tid;
      int row = c >> 3, c8 = c & 7;
      *(float4*)(&Ks[row * 88 + c8 * 8]) =
          *(const float4*)(&Kb[(size_t)(kt + row) * DK + c8 * 8]);
    }
#pragma unroll
    for (int i = 0; i < 4; i++) {
      int e = i * 256 + tid;
      int k = e >> 5, d2 = e & 31;
      u32 v = *(const u32*)(&Vb[(size_t)(kt + k) * DK + d2 * 2]);
      Vs[(d2 * 2)     * 40 + k] = (u16)(v & 0xffffu);
      Vs[(d2 * 2 + 1) * 40 + k] = (u16)(v >> 16);
    }
    __syncthreads();
    f32x4 sc[2] = {};
#pragma unroll
    for (int ktt = 0; ktt < 2; ktt++)
#pragma unroll
      for (int dk = 0; dk < 2; dk++) {
        bf16x8 kf = *(const bf16x8*)(&Ks[(ktt * 16 + l15) * 88 + dk * 32 + quad * 8]);
        sc[ktt] = __builtin_amdgcn_mfma_f32_16x16x32_bf16(qf[dk], kf, sc[ktt], 0, 0, 0);
      }
    float alph[4];
#pragma unroll
    for (int r = 0; r < 4; r++) {
      float s0 = sc[0][r] * 0.125f;
      float s1 = sc[1][r] * 0.125f;
      float mv = fmaxf(s0, s1);
      mv = fmaxf(mv, __shfl_xor(mv, 1));
      mv = fmaxf(mv, __shfl_xor(mv, 2));
      mv = fmaxf(mv, __shfl_xor(mv, 4));
      mv = fmaxf(mv, __shfl_xor(mv, 8));
      float mnew = fmaxf(m_i[r], mv);
      float a = __expf(m_i[r] - mnew);
      m_i[r] = mnew;
      float p0 = __expf(s0 - mnew);
      float p1 = __expf(s1 - mnew);
      float rs = p0 + p1;
      rs += __shfl_xor(rs, 1);
      rs += __shfl_xor(rs, 2);
      rs += __shfl_xor(rs, 4);
      rs += __shfl_xor(rs, 8);
      l_i[r] = l_i[r] * a + rs;
      alph[r] = a;
      Ps[w][(quad * 4 + r) * 32 +      l15] = f2b(p0);
      Ps[w][(quad * 4 + r) * 32 + 16 + l15] = f2b(p1);
    }
#pragma unroll
    for (int nt = 0; nt < 4; nt++) {
      acc[nt][0] *= alph[0];
      acc[nt][1] *= alph[1];
      acc[nt][2] *= alph[2];
      acc[nt][3] *= alph[3];
    }
    __syncthreads();
    bf16x8 pf = *(const bf16x8*)(&Ps[w][l15 * 32 + quad * 8]);
#pragma unroll
    for (int nt = 0; nt < 4; nt++) {
      bf16x8 vf = *(const bf16x8*)(&Vs[(nt * 16 + l15) * 40 + quad * 8]);
      acc[nt] = __builtin_amdgcn_mfma_f32_16x16x32_bf16(pf, vf, acc[nt], 0, 0, 0);
    }
  }
#pragma unroll
  for (int nt = 0; nt < 4; nt++) {
    int d = nt * 16 + l15;
#pragma unroll
    for (int r = 0; r < 4; r++) {
      int s = q0 + quad * 4 + r;
      float v = acc[nt][r] / l_i[r];
      ctx[((size_t)(b * SEQ + s)) * DM + h * DK + d] = f2b(v);
    }
  }
}

// ---------------- HOST ----------------

extern "C" void kernel_launch(void* const* d_in, const int* in_sizes, int n_in,
                              void* d_out, int out_size, void* d_ws, size_t ws_size,
                              hipStream_t stream) {
  const float* act[3] = {nullptr, nullptr, nullptr};
  const float* wgt[4] = {nullptr, nullptr, nullptr, nullptr};
  int na = 0, nw = 0;
  for (int i = 0; i < n_in && i < 7; i++) {
    if (in_sizes[i] == NEL) { if (na < 3) act[na++] = (const float*)d_in[i]; }
    else                    { if (nw < 4) wgt[nw++] = (const float*)d_in[i]; }
  }
  const float* q  = act[0] ? act[0] : (const float*)d_in[0];
  const float* k  = act[1] ? act[1] : (const float*)d_in[1];
  const float* v  = act[2] ? act[2] : (const float*)d_in[2];
  const float* Wq = wgt[0] ? wgt[0] : (const float*)d_in[3];
  const float* Wk = wgt[1] ? wgt[1] : (const float*)d_in[4];
  const float* Wv = wgt[2] ? wgt[2] : (const float*)d_in[5];
  const float* Wo = wgt[3] ? wgt[3] : (const float*)d_in[6];
  u16* ws = (u16*)d_ws;

  const size_t NE = NEL, NW = NWL;
  const size_t need = (6 * NE + 4 * NW) * 2;   // 42.47 MB

  if (ws_size >= need) {
    u16* Xb  = ws;                 // 3*NE ; later aliased by Ctx
    u16* Wb  = ws + 3 * NE;        // 4*NW
    u16* Qhm = Wb + 4 * NW;
    u16* Khm = Qhm + NE;
    u16* Vt  = Khm + NE;
    u16* Ctx = ws;                 // alias Xb (dead after qkv2)

    to_bf16<<<5760, 256, 0, stream>>>(q, k, v, Wq, Wk, Wv, Wo, Xb, Wb);
    qkv2<<<dim3(DM / 128, MTOT / 128, 3), 256, 0, stream>>>(Xb, Wb, Qhm, Khm, Vt);
    attn3<<<dim3(SEQ / 64, NBH), 256, 0, stream>>>(Qhm, Khm, Vt, Ctx);
    bt2<<<dim3(DM / 128, MTOT / 128), 256, 0, stream>>>(Ctx, Wb + 3 * NW, (float*)d_out);
  } else {
    u16* Qhm = ws;
    u16* Khm = ws + NE;
    u16* Vhm = ws + 2 * NE;
    u16* Ctx = ws + 3 * NE;
    fb_qkv_gemm<<<dim3(DM / 128, MTOT / 128, 3), 256, 0, stream>>>(
        q, k, v, Wq, Wk, Wv, Qhm, Khm, Vhm);
    fb_attn<<<dim3(SEQ / 64, NBH), 256, 0, stream>>>(Qhm, Khm, Vhm, Ctx);
    fb_gemm_bt<<<dim3(DM / 128, MTOT / 128), 256, 0, stream>>>(Ctx, Wo, (float*)d_out);
  }
}

// Round 8
// 196.441 us; speedup vs baseline: 2.0719x; 2.0719x over previous
//
#include <hip/hip_runtime.h>
#include <hip/hip_bf16.h>

// MultiHeadAttention B=2,S=2048,D=768,H=12,Dk=64. fp32 in, fp32 out (proven R4).
// FAST: [to_bf16] -> [qkv2: BK=64 gl_lds GEMM; Q scaled by 0.125*log2e in epilogue;
// V stored transposed+pos32-permuted] -> [attn3: wave=64q x 32keys, exp2-only
// softmax (no max/clamp), l via ones-MFMA, 4-wave merge] -> [bt2 fp32 out].
// R7 fix: attn3 final store used oacc[w][..] with RUNTIME w -> whole acc array
// spilled to scratch (851 MB WRITE_SIZE, MfmaUtil 4%). Now compile-time indices.
// FALLBACK (small ws): round-4 proven pipeline.
// Verified MFMA 16x16x32 layouts: A[m=l15][k=quad*8+j], B[n=l15][k=quad*8+j],
// C/D col=l15 row=quad*4+reg.
// xor-swizzle: LDS slot (row,c8) holds global chunk (c8^(row&7)) [K/A/B] or
// (c16^(d&15)) [V] -> conflict-free b128 reads with lane-linear gl_lds dst
// (verified R7: SQ_LDS_BANK_CONFLICT = 0).

typedef __bf16 bf16x8 __attribute__((ext_vector_type(8)));
typedef float f32x4 __attribute__((ext_vector_type(4)));
typedef unsigned short u16;
typedef unsigned int u32;
typedef u16 u16x8 __attribute__((ext_vector_type(8)));
typedef u16 u16x4 __attribute__((ext_vector_type(4)));

#define SEQ 2048
#define DM  768
#define NH  12
#define DK  64
#define NBH 24
#define MTOT 4096
#define NEL 3145728   // MTOT*DM
#define NWL 589824    // DM*DM
#define QSCALE 0.18033688f   // 0.125 * log2(e): scores pre-scaled for exp2

__device__ __forceinline__ u16 f2b(float v) {
  __bf16 t = (__bf16)v;
  return __builtin_bit_cast(u16, t);
}

__device__ __forceinline__ void gl_lds16(const u16* g, u16* l) {
  __builtin_amdgcn_global_load_lds(
      (const __attribute__((address_space(1))) void*)g,
      (__attribute__((address_space(3))) void*)l, 16, 0, 0);
}

// key permutation within 32-groups so P's MFMA B-frag register order (k=quad*8+j)
// matches V's stored column order: pos32(MT*16+quad*4+r) = quad*8 + MT*4 + r.
__device__ __forceinline__ int pos32(int k) {
  return (k < 16) ? (((k >> 2) << 3) + (k & 3))
                  : ((((k & 15) >> 2) << 3) + (k & 3) + 4);
}

// ---------------- FAST PATH ----------------

__global__ __launch_bounds__(256) void to_bf16(
    const float* __restrict__ s0, const float* __restrict__ s1, const float* __restrict__ s2,
    const float* __restrict__ s3, const float* __restrict__ s4, const float* __restrict__ s5,
    const float* __restrict__ s6, u16* __restrict__ Xb, u16* __restrict__ Wb)
{
  size_t c = (size_t)blockIdx.x * 256 + threadIdx.x;
  const float* src;
  u16* dst;
  if (c < 1179648) {
    int seg = (int)(c / 393216);
    size_t off = (c % 393216) * 8;
    src = (seg == 0 ? s0 : seg == 1 ? s1 : s2) + off;
    dst = Xb + (size_t)seg * NEL + off;
  } else {
    size_t c2 = c - 1179648;
    int seg = (int)(c2 / 73728);
    size_t off = (c2 % 73728) * 8;
    src = (seg == 0 ? s3 : seg == 1 ? s4 : seg == 2 ? s5 : s6) + off;
    dst = Wb + (size_t)seg * NWL + off;
  }
  float4 f0 = *(const float4*)(src);
  float4 f1 = *(const float4*)(src + 4);
  u16x8 o;
  o[0] = f2b(f0.x); o[1] = f2b(f0.y); o[2] = f2b(f0.z); o[3] = f2b(f0.w);
  o[4] = f2b(f1.x); o[5] = f2b(f1.y); o[6] = f2b(f1.z); o[7] = f2b(f1.w);
  *(u16x8*)dst = o;
}

// 128x128 tile GEMM, BK=64, gl_lds + xor swizzle. modes: 0 head-major bf16
// (scaled) via LDS-transpose; 1 Vt (d-major, pos32 s); 2 fp32 row-major.
__device__ __forceinline__ void gemm2_core(
    const u16* __restrict__ X, const u16* __restrict__ W, void* __restrict__ Y,
    int m0, int n0, int mode, float scale, u16* As, u16* Bs)
{
  const int tid  = threadIdx.x;
  const int lane = tid & 63, w = tid >> 6;
  const int l15  = lane & 15, quad = lane >> 4;
  const int wm   = (w & 1) * 64, wn = (w >> 1) * 64;

  f32x4 acc[4][4] = {};

  for (int k0 = 0; k0 < DM; k0 += 64) {
    __syncthreads();
#pragma unroll
    for (int i = 0; i < 4; i++) {
      int c = (w * 4 + i) * 64 + lane;
      int row = c >> 3, c8 = c & 7;
      int g8 = c8 ^ (row & 7);
      gl_lds16(X + (size_t)(m0 + row) * DM + k0 + g8 * 8, As + c * 8);
      gl_lds16(W + (size_t)(n0 + row) * DM + k0 + g8 * 8, Bs + c * 8);
    }
    __syncthreads();
#pragma unroll
    for (int dk = 0; dk < 2; dk++) {
      bf16x8 af[4], bf[4];
      int ph = ((dk * 4 + quad) ^ (l15 & 7)) * 8;
#pragma unroll
      for (int t = 0; t < 4; t++) {
        af[t] = *(const bf16x8*)(&As[(wm + t * 16 + l15) * 64 + ph]);
        bf[t] = *(const bf16x8*)(&Bs[(wn + t * 16 + l15) * 64 + ph]);
      }
#pragma unroll
      for (int mt = 0; mt < 4; mt++)
#pragma unroll
        for (int nt = 0; nt < 4; nt++)
          acc[mt][nt] = __builtin_amdgcn_mfma_f32_16x16x32_bf16(af[mt], bf[nt], acc[mt][nt], 0, 0, 0);
    }
  }

  if (mode == 2) {
    float* O = (float*)Y;
#pragma unroll
    for (int mt = 0; mt < 4; mt++) {
      int mg = m0 + wm + mt * 16 + quad * 4;
#pragma unroll
      for (int nt = 0; nt < 4; nt++) {
        int j = n0 + wn + nt * 16 + l15;
#pragma unroll
        for (int r = 0; r < 4; r++)
          O[(size_t)(mg + r) * DM + j] = acc[mt][nt][r];
      }
    }
  } else if (mode == 1) {       // Vt[bh][d][s']
    u16* O = (u16*)Y;
#pragma unroll
    for (int mt = 0; mt < 4; mt++) {
      int mg = m0 + wm + mt * 16 + quad * 4;
      int b = mg >> 11, s = mg & 2047;
      int sp = (s & ~31) | pos32(s & 31);
#pragma unroll
      for (int nt = 0; nt < 4; nt++) {
        int j = n0 + wn + nt * 16 + l15;
        int h = j >> 6, d = j & 63;
        u16x4 o;
#pragma unroll
        for (int r = 0; r < 4; r++) o[r] = f2b(acc[mt][nt][r]);
        *(u16x4*)&O[((size_t)(b * NH + h) * DK + d) * SEQ + sp] = o;
      }
    }
  } else {                      // head-major via LDS transpose, scaled
    u16* O = (u16*)Y;
    u16* T = As;
#pragma unroll
    for (int h2 = 0; h2 < 2; h2++) {
      __syncthreads();
      if ((w & 1) == h2) {
#pragma unroll
        for (int mt = 0; mt < 4; mt++)
#pragma unroll
          for (int nt = 0; nt < 4; nt++)
#pragma unroll
            for (int r = 0; r < 4; r++)
              T[(mt * 16 + quad * 4 + r) * 128 + wn + nt * 16 + l15] = f2b(acc[mt][nt][r] * scale);
      }
      __syncthreads();
#pragma unroll
      for (int i = 0; i < 4; i++) {
        int c = i * 256 + tid;
        int row = c >> 4, ch = c & 15;
        u16x8 val = *(const u16x8*)&T[row * 128 + ch * 8];
        int m = m0 + h2 * 64 + row;
        int j = n0 + ch * 8;
        int hh = j >> 6, d = j & 63;
        int b = m >> 11, s = m & 2047;
        *(u16x8*)&O[((size_t)(b * NH + hh) * SEQ + s) * DK + d] = val;
      }
    }
  }
}

__global__ __launch_bounds__(256) void qkv2(
    const u16* __restrict__ Xb, const u16* __restrict__ Wb,
    u16* __restrict__ Qhm, u16* __restrict__ Khm, u16* __restrict__ Vt)
{
  __shared__ __align__(16) u16 As[128 * 64];
  __shared__ __align__(16) u16 Bs[128 * 64];
  int mat = blockIdx.z;
  const u16* X = Xb + (size_t)mat * NEL;
  const u16* W = Wb + (size_t)mat * NWL;
  void* Y = (mat == 0) ? (void*)Qhm : (mat == 1) ? (void*)Khm : (void*)Vt;
  float scale = (mat == 0) ? QSCALE : 1.0f;
  gemm2_core(X, W, Y, blockIdx.y * 128, blockIdx.x * 128, (mat == 2) ? 1 : 0, scale, As, Bs);
}

__global__ __launch_bounds__(256) void bt2(
    const u16* __restrict__ Ctx, const u16* __restrict__ Wob, float* __restrict__ Y)
{
  __shared__ __align__(16) u16 As[128 * 64];
  __shared__ __align__(16) u16 Bs[128 * 64];
  gemm2_core(Ctx, Wob, Y, blockIdx.y * 128, blockIdx.x * 128, 2, 1.0f, As, Bs);
}

// attn3: grid (32,24), 4 waves. Each wave: ALL 64 q, its own 32-key quarter of
// each 128-key tile. Q pre-scaled by QSCALE -> p = exp2(sc), no max/clamp.
// l via ones-A MFMA. Epilogue: 4-wave partial-O merge (DT-owner), then store.
// ALL register-array indices compile-time constant (R7 spill lesson).
__global__ __launch_bounds__(256, 3) void attn3(
    const u16* __restrict__ Qh, const u16* __restrict__ Kh,
    const u16* __restrict__ Vt, u16* __restrict__ ctx)
{
  __shared__ __align__(16) u16 smem[128 * 64 + 64 * 128];  // 32 KB: Ks | Vs; reused as merge buf
  __shared__ float Lsum[4][64];
  u16* Ks = smem;
  u16* Vs = smem + 128 * 64;

  const int tid  = threadIdx.x;
  const int lane = tid & 63, w = tid >> 6;
  const int l15  = lane & 15, quad = lane >> 4;
  const int qt = blockIdx.x, bh = blockIdx.y;
  const int b = bh / NH, h = bh % NH;

  const u16* Qb = Qh + (size_t)bh * SEQ * DK;
  const u16* Kb = Kh + (size_t)bh * SEQ * DK;
  const u16* Vb = Vt + (size_t)bh * DK * SEQ;
  const int q0 = qt * 64;

  bf16x8 qf[4][2];   // B[n=q][k=d]
#pragma unroll
  for (int QT = 0; QT < 4; QT++)
#pragma unroll
    for (int dk = 0; dk < 2; dk++)
      qf[QT][dk] = *(const bf16x8*)&Qb[(size_t)(q0 + QT * 16 + l15) * DK + dk * 32 + quad * 8];

  bf16x8 onef;
#pragma unroll
  for (int j = 0; j < 8; j++) onef[j] = (__bf16)1.0f;

  f32x4 oacc[4][4] = {};   // [DT][QT]  O^T: col=q, row=d
  f32x4 lacc[4] = {};      // [QT] row-sums of P (all 4 r equal)

  for (int kt = 0; kt < SEQ; kt += 128) {
    __syncthreads();
#pragma unroll
    for (int i = 0; i < 4; i++) {
      int c = (w * 4 + i) * 64 + lane;   // K: 1024 chunks, row=c>>3
      int row = c >> 3, c8 = c & 7;
      gl_lds16(Kb + (size_t)(kt + row) * DK + (c8 ^ (row & 7)) * 8, Ks + c * 8);
    }
#pragma unroll
    for (int i = 0; i < 4; i++) {
      int c = (w * 4 + i) * 64 + lane;   // V: 1024 chunks, d=c>>4
      int d = c >> 4, c16 = c & 15;
      gl_lds16(Vb + (size_t)d * SEQ + kt + (c16 ^ (d & 15)) * 8, Vs + c * 8);
    }
    __syncthreads();

    // S^T[key][q]: this wave's 32-key quarter, all 64 q
    f32x4 sc[2][4] = {};
#pragma unroll
    for (int MT = 0; MT < 2; MT++) {
      int row = w * 32 + MT * 16 + l15;
#pragma unroll
      for (int dk = 0; dk < 2; dk++) {
        bf16x8 kf = *(const bf16x8*)&Ks[row * 64 + ((dk * 4 + quad) ^ (l15 & 7)) * 8];
#pragma unroll
        for (int QT = 0; QT < 4; QT++)
          sc[MT][QT] = __builtin_amdgcn_mfma_f32_16x16x32_bf16(kf, qf[QT][dk], sc[MT][QT], 0, 0, 0);
      }
    }

    // p = exp2(sc) straight into PV B-frag order; l via ones-MFMA
    bf16x8 pf[4];
#pragma unroll
    for (int QT = 0; QT < 4; QT++) {
#pragma unroll
      for (int j = 0; j < 8; j++)
        pf[QT][j] = (__bf16)__builtin_amdgcn_exp2f(sc[j >> 2][QT][j & 3]);
      lacc[QT] = __builtin_amdgcn_mfma_f32_16x16x32_bf16(onef, pf[QT], lacc[QT], 0, 0, 0);
    }

    // O^T += V^T * P
    int cL = w * 4 + quad;
#pragma unroll
    for (int DT = 0; DT < 4; DT++) {
      int d = DT * 16 + l15;
      bf16x8 vf = *(const bf16x8*)&Vs[d * 128 + (cL ^ (d & 15)) * 8];
#pragma unroll
      for (int QT = 0; QT < 4; QT++)
        oacc[DT][QT] = __builtin_amdgcn_mfma_f32_16x16x32_bf16(vf, pf[QT], oacc[DT][QT], 0, 0, 0);
    }
  }

  __syncthreads();   // tile reads done; smem becomes merge buffer

  if (quad == 0) {
#pragma unroll
    for (int QT = 0; QT < 4; QT++)
      Lsum[w][QT * 16 + l15] = lacc[QT][0];
  }

  // merge partial O across waves: wave w owns DT=w; two rounds of DT pairs.
  // buf region (0..5): [64 q][18 pad] f32 = 4608 B; total 27648 B <= 32 KB.
  float* fb = (float*)smem;
#pragma unroll
  for (int rd = 0; rd < 2; rd++) {
    int p0 = rd * 2, p1 = rd * 2 + 1;
    __syncthreads();
    if (w != p0) {
      int s3 = (w < p0) ? w : w - 1;
#pragma unroll
      for (int QT = 0; QT < 4; QT++)
        *(f32x4*)&fb[(0 * 3 + s3) * 1152 + (QT * 16 + l15) * 18 + quad * 4] = oacc[p0][QT];
    }
    if (w != p1) {
      int s3 = (w < p1) ? w : w - 1;
#pragma unroll
      for (int QT = 0; QT < 4; QT++)
        *(f32x4*)&fb[(1 * 3 + s3) * 1152 + (QT * 16 + l15) * 18 + quad * 4] = oacc[p1][QT];
    }
    __syncthreads();
    if (w == p0) {
#pragma unroll
      for (int s3 = 0; s3 < 3; s3++)
#pragma unroll
        for (int QT = 0; QT < 4; QT++)
          oacc[p0][QT] += *(const f32x4*)&fb[(0 * 3 + s3) * 1152 + (QT * 16 + l15) * 18 + quad * 4];
    }
    if (w == p1) {
#pragma unroll
      for (int s3 = 0; s3 < 3; s3++)
#pragma unroll
        for (int QT = 0; QT < 4; QT++)
          oacc[p1][QT] += *(const f32x4*)&fb[(1 * 3 + s3) * 1152 + (QT * 16 + l15) * 18 + quad * 4];
    }
  }

  // wave w stores its DT=w tile, normalized by total l.
  // COMPILE-TIME indices only: unrolled DT loop guarded by (w == DT).
#pragma unroll
  for (int DT = 0; DT < 4; DT++) {
    if (w == DT) {
#pragma unroll
      for (int QT = 0; QT < 4; QT++) {
        int q = QT * 16 + l15;
        float inv = 1.0f / (Lsum[0][q] + Lsum[1][q] + Lsum[2][q] + Lsum[3][q]);
        u16x4 ov;
#pragma unroll
        for (int r = 0; r < 4; r++)
          ov[r] = f2b(oacc[DT][QT][r] * inv);
        *(u16x4*)&ctx[((size_t)(b * SEQ + q0 + q)) * DM + h * DK + DT * 16 + quad * 4] = ov;
      }
    }
  }
}

// ---------------- FALLBACK PATH (round-4, proven) ----------------

__device__ __forceinline__ void stage8(u16* dst, const void* src, size_t elemIdx, int isf32) {
  if (isf32) {
    const float* s = (const float*)src + elemIdx;
    float4 f0 = *(const float4*)(s);
    float4 f1 = *(const float4*)(s + 4);
    u16x8 o;
    o[0] = f2b(f0.x); o[1] = f2b(f0.y); o[2] = f2b(f0.z); o[3] = f2b(f0.w);
    o[4] = f2b(f1.x); o[5] = f2b(f1.y); o[6] = f2b(f1.z); o[7] = f2b(f1.w);
    *(u16x8*)dst = o;
  } else {
    *(float4*)dst = *(const float4*)((const u16*)src + elemIdx);
  }
}

__device__ __forceinline__ void gemm_core_fb(
    const void* __restrict__ X, const void* __restrict__ W, void* __restrict__ Y,
    int m0, int n0, int out_mode, u16* As, u16* Bs, int xf32, int wf32)
{
  const int tid  = threadIdx.x;
  const int lane = tid & 63, w = tid >> 6;
  const int l15  = lane & 15, quad = lane >> 4;
  const int wm   = (w & 1) * 64, wn = (w >> 1) * 64;
  f32x4 acc[4][4] = {};
  for (int k0 = 0; k0 < DM; k0 += 32) {
    __syncthreads();
#pragma unroll
    for (int i = 0; i < 2; i++) {
      int c = i * 256 + tid;
      int row = c >> 2, cc = c & 3;
      stage8(&As[c * 8], X, (size_t)(m0 + row) * DM + k0 + cc * 8, xf32);
      stage8(&Bs[c * 8], W, (size_t)(n0 + row) * DM + k0 + cc * 8, wf32);
    }
    __syncthreads();
    bf16x8 af[4], bf[4];
#pragma unroll
    for (int t = 0; t < 4; t++) {
      af[t] = *(const bf16x8*)(&As[(wm + t * 16 + l15) * 32 + quad * 8]);
      bf[t] = *(const bf16x8*)(&Bs[(wn + t * 16 + l15) * 32 + quad * 8]);
    }
#pragma unroll
    for (int mt = 0; mt < 4; mt++)
#pragma unroll
      for (int nt = 0; nt < 4; nt++)
        acc[mt][nt] = __builtin_amdgcn_mfma_f32_16x16x32_bf16(af[mt], bf[nt], acc[mt][nt], 0, 0, 0);
  }
  if (out_mode == 2) {
    float* O = (float*)Y;
#pragma unroll
    for (int mt = 0; mt < 4; mt++) {
      int mg = m0 + wm + mt * 16 + quad * 4;
#pragma unroll
      for (int nt = 0; nt < 4; nt++) {
        int j = n0 + wn + nt * 16 + l15;
#pragma unroll
        for (int r = 0; r < 4; r++)
          O[(size_t)(mg + r) * DM + j] = acc[mt][nt][r];
      }
    }
  } else {
    u16* O = (u16*)Y;
#pragma unroll
    for (int mt = 0; mt < 4; mt++) {
      int mg = m0 + wm + mt * 16 + quad * 4;
#pragma unroll
      for (int nt = 0; nt < 4; nt++) {
        int j = n0 + wn + nt * 16 + l15;
        int h = j >> 6, d = j & 63;
#pragma unroll
        for (int r = 0; r < 4; r++) {
          int m = mg + r;
          int b = m >> 11, s = m & 2047;
          O[((size_t)(b * NH + h) * SEQ + s) * DK + d] = f2b(acc[mt][nt][r]);
        }
      }
    }
  }
}

__global__ __launch_bounds__(256) void fb_qkv_gemm(
    const float* __restrict__ Xq, const float* __restrict__ Xk, const float* __restrict__ Xv,
    const float* __restrict__ Wq, const float* __restrict__ Wk, const float* __restrict__ Wv,
    u16* __restrict__ Yq, u16* __restrict__ Yk, u16* __restrict__ Yv)
{
  __shared__ __align__(16) u16 As[128 * 32];
  __shared__ __align__(16) u16 Bs[128 * 32];
  int mat = blockIdx.z;
  const float* X = (mat == 0) ? Xq : (mat == 1) ? Xk : Xv;
  const float* W = (mat == 0) ? Wq : (mat == 1) ? Wk : Wv;
  u16*         Y = (mat == 0) ? Yq : (mat == 1) ? Yk : Yv;
  gemm_core_fb(X, W, Y, blockIdx.y * 128, blockIdx.x * 128, 0, As, Bs, 1, 1);
}

__global__ __launch_bounds__(256) void fb_gemm_bt(
    const u16* __restrict__ X, const float* __restrict__ W, float* __restrict__ Y)
{
  __shared__ __align__(16) u16 As[128 * 32];
  __shared__ __align__(16) u16 Bs[128 * 32];
  gemm_core_fb(X, W, Y, blockIdx.y * 128, blockIdx.x * 128, 2, As, Bs, 0, 1);
}

__global__ __launch_bounds__(256) void fb_attn(
    const u16* __restrict__ Qh, const u16* __restrict__ Kh,
    const u16* __restrict__ Vh, u16* __restrict__ ctx)
{
  __shared__ __align__(16) u16 Ks[32 * 88];
  __shared__ __align__(16) u16 Vs[64 * 40];
  __shared__ __align__(16) u16 Ps[4][16 * 32];
  const int tid  = threadIdx.x;
  const int lane = tid & 63, w = tid >> 6;
  const int l15  = lane & 15, quad = lane >> 4;
  const int qt = blockIdx.x, bh = blockIdx.y;
  const int b = bh / NH, h = bh % NH;
  const u16* Qb = Qh + (size_t)bh * SEQ * DK;
  const u16* Kb = Kh + (size_t)bh * SEQ * DK;
  const u16* Vb = Vh + (size_t)bh * SEQ * DK;
  const int q0 = qt * 64 + w * 16;
  bf16x8 qf[2];
#pragma unroll
  for (int kk = 0; kk < 2; kk++)
    qf[kk] = *(const bf16x8*)(&Qb[(size_t)(q0 + l15) * DK + kk * 32 + quad * 8]);
  float m_i[4] = {-INFINITY, -INFINITY, -INFINITY, -INFINITY};
  float l_i[4] = {0.f, 0.f, 0.f, 0.f};
  f32x4 acc[4] = {};
  for (int kt = 0; kt < SEQ; kt += 32) {
    __syncthreads();
    {
      int c = tid;
      int row = c >> 3, c8 = c & 7;
      *(float4*)(&Ks[row * 88 + c8 * 8]) =
          *(const float4*)(&Kb[(size_t)(kt + row) * DK + c8 * 8]);
    }
#pragma unroll
    for (int i = 0; i < 4; i++) {
      int e = i * 256 + tid;
      int k = e >> 5, d2 = e & 31;
      u32 v = *(const u32*)(&Vb[(size_t)(kt + k) * DK + d2 * 2]);
      Vs[(d2 * 2)     * 40 + k] = (u16)(v & 0xffffu);
      Vs[(d2 * 2 + 1) * 40 + k] = (u16)(v >> 16);
    }
    __syncthreads();
    f32x4 sc[2] = {};
#pragma unroll
    for (int ktt = 0; ktt < 2; ktt++)
#pragma unroll
      for (int dk = 0; dk < 2; dk++) {
        bf16x8 kf = *(const bf16x8*)(&Ks[(ktt * 16 + l15) * 88 + dk * 32 + quad * 8]);
        sc[ktt] = __builtin_amdgcn_mfma_f32_16x16x32_bf16(qf[dk], kf, sc[ktt], 0, 0, 0);
      }
    float alph[4];
#pragma unroll
    for (int r = 0; r < 4; r++) {
      float s0 = sc[0][r] * 0.125f;
      float s1 = sc[1][r] * 0.125f;
      float mv = fmaxf(s0, s1);
      mv = fmaxf(mv, __shfl_xor(mv, 1));
      mv = fmaxf(mv, __shfl_xor(mv, 2));
      mv = fmaxf(mv, __shfl_xor(mv, 4));
      mv = fmaxf(mv, __shfl_xor(mv, 8));
      float mnew = fmaxf(m_i[r], mv);
      float a = __expf(m_i[r] - mnew);
      m_i[r] = mnew;
      float p0 = __expf(s0 - mnew);
      float p1 = __expf(s1 - mnew);
      float rs = p0 + p1;
      rs += __shfl_xor(rs, 1);
      rs += __shfl_xor(rs, 2);
      rs += __shfl_xor(rs, 4);
      rs += __shfl_xor(rs, 8);
      l_i[r] = l_i[r] * a + rs;
      alph[r] = a;
      Ps[w][(quad * 4 + r) * 32 +      l15] = f2b(p0);
      Ps[w][(quad * 4 + r) * 32 + 16 + l15] = f2b(p1);
    }
#pragma unroll
    for (int nt = 0; nt < 4; nt++) {
      acc[nt][0] *= alph[0];
      acc[nt][1] *= alph[1];
      acc[nt][2] *= alph[2];
      acc[nt][3] *= alph[3];
    }
    __syncthreads();
    bf16x8 pf = *(const bf16x8*)(&Ps[w][l15 * 32 + quad * 8]);
#pragma unroll
    for (int nt = 0; nt < 4; nt++) {
      bf16x8 vf = *(const bf16x8*)(&Vs[(nt * 16 + l15) * 40 + quad * 8]);
      acc[nt] = __builtin_amdgcn_mfma_f32_16x16x32_bf16(pf, vf, acc[nt], 0, 0, 0);
    }
  }
#pragma unroll
  for (int nt = 0; nt < 4; nt++) {
    int d = nt * 16 + l15;
#pragma unroll
    for (int r = 0; r < 4; r++) {
      int s = q0 + quad * 4 + r;
      float v = acc[nt][r] / l_i[r];
      ctx[((size_t)(b * SEQ + s)) * DM + h * DK + d] = f2b(v);
    }
  }
}

// ---------------- HOST ----------------

extern "C" void kernel_launch(void* const* d_in, const int* in_sizes, int n_in,
                              void* d_out, int out_size, void* d_ws, size_t ws_size,
                              hipStream_t stream) {
  const float* act[3] = {nullptr, nullptr, nullptr};
  const float* wgt[4] = {nullptr, nullptr, nullptr, nullptr};
  int na = 0, nw = 0;
  for (int i = 0; i < n_in && i < 7; i++) {
    if (in_sizes[i] == NEL) { if (na < 3) act[na++] = (const float*)d_in[i]; }
    else                    { if (nw < 4) wgt[nw++] = (const float*)d_in[i]; }
  }
  const float* q  = act[0] ? act[0] : (const float*)d_in[0];
  const float* k  = act[1] ? act[1] : (const float*)d_in[1];
  const float* v  = act[2] ? act[2] : (const float*)d_in[2];
  const float* Wq = wgt[0] ? wgt[0] : (const float*)d_in[3];
  const float* Wk = wgt[1] ? wgt[1] : (const float*)d_in[4];
  const float* Wv = wgt[2] ? wgt[2] : (const float*)d_in[5];
  const float* Wo = wgt[3] ? wgt[3] : (const float*)d_in[6];
  u16* ws = (u16*)d_ws;

  const size_t NE = NEL, NW = NWL;
  const size_t need = (6 * NE + 4 * NW) * 2;   // 42.47 MB

  if (ws_size >= need) {
    u16* Xb  = ws;                 // 3*NE ; later aliased by Ctx
    u16* Wb  = ws + 3 * NE;        // 4*NW
    u16* Qhm = Wb + 4 * NW;
    u16* Khm = Qhm + NE;
    u16* Vt  = Khm + NE;
    u16* Ctx = ws;                 // alias Xb (dead after qkv2)

    to_bf16<<<5760, 256, 0, stream>>>(q, k, v, Wq, Wk, Wv, Wo, Xb, Wb);
    qkv2<<<dim3(DM / 128, MTOT / 128, 3), 256, 0, stream>>>(Xb, Wb, Qhm, Khm, Vt);
    attn3<<<dim3(SEQ / 64, NBH), 256, 0, stream>>>(Qhm, Khm, Vt, Ctx);
    bt2<<<dim3(DM / 128, MTOT / 128), 256, 0, stream>>>(Ctx, Wb + 3 * NW, (float*)d_out);
  } else {
    u16* Qhm = ws;
    u16* Khm = ws + NE;
    u16* Vhm = ws + 2 * NE;
    u16* Ctx = ws + 3 * NE;
    fb_qkv_gemm<<<dim3(DM / 128, MTOT / 128, 3), 256, 0, stream>>>(
        q, k, v, Wq, Wk, Wv, Qhm, Khm, Vhm);
    fb_attn<<<dim3(SEQ / 64, NBH), 256, 0, stream>>>(Qhm, Khm, Vhm, Ctx);
    fb_gemm_bt<<<dim3(DM / 128, MTOT / 128), 256, 0, stream>>>(Ctx, Wo, (float*)d_out);
  }
}

// Round 9
// 190.888 us; speedup vs baseline: 2.1322x; 1.0291x over previous
//
#include <hip/hip_runtime.h>
#include <hip/hip_bf16.h>

// MultiHeadAttention B=2,S=2048,D=768,H=12,Dk=64. fp32 in, fp32 out (proven R4).
// FAST: [to_bf16] -> [qkv2] -> [attn3] -> [bt2]. R9: XCD-aware linear-grid
// swizzle (xcd = blockIdx.x % 8, per m09 round-robin heuristic) so L2 reuse is
// XCD-local: attn3 gives each XCD 3 whole bh (K/V fetched from HBM once);
// qkv2/bt2 give each XCD 4 m-blocks x all (n,mat), mat slowest (working set
// ~2 MB < 4 MB L2/XCD). R8 evidence: attn3 FETCH 58.7MB = ~3x unique bytes,
// both pipes <25% busy -> HBM-latency-bound on cross-XCD re-fetch.
// R7 lesson kept: all register-array indices compile-time constant.
// FALLBACK (small ws): round-4 proven pipeline.
// Verified MFMA 16x16x32 layouts: A[m=l15][k=quad*8+j], B[n=l15][k=quad*8+j],
// C/D col=l15 row=quad*4+reg.
// xor-swizzle: LDS slot (row,c8) holds global chunk (c8^(row&7)) [K/A/B] or
// (c16^(d&15)) [V] -> conflict-free (R7/R8: SQ_LDS_BANK_CONFLICT = 0).

typedef __bf16 bf16x8 __attribute__((ext_vector_type(8)));
typedef float f32x4 __attribute__((ext_vector_type(4)));
typedef unsigned short u16;
typedef unsigned int u32;
typedef u16 u16x8 __attribute__((ext_vector_type(8)));
typedef u16 u16x4 __attribute__((ext_vector_type(4)));

#define SEQ 2048
#define DM  768
#define NH  12
#define DK  64
#define NBH 24
#define MTOT 4096
#define NEL 3145728   // MTOT*DM
#define NWL 589824    // DM*DM
#define QSCALE 0.18033688f   // 0.125 * log2(e): scores pre-scaled for exp2

__device__ __forceinline__ u16 f2b(float v) {
  __bf16 t = (__bf16)v;
  return __builtin_bit_cast(u16, t);
}

__device__ __forceinline__ void gl_lds16(const u16* g, u16* l) {
  __builtin_amdgcn_global_load_lds(
      (const __attribute__((address_space(1))) void*)g,
      (__attribute__((address_space(3))) void*)l, 16, 0, 0);
}

// key permutation within 32-groups so P's MFMA B-frag register order (k=quad*8+j)
// matches V's stored column order: pos32(MT*16+quad*4+r) = quad*8 + MT*4 + r.
__device__ __forceinline__ int pos32(int k) {
  return (k < 16) ? (((k >> 2) << 3) + (k & 3))
                  : ((((k & 15) >> 2) << 3) + (k & 3) + 4);
}

// ---------------- FAST PATH ----------------

__global__ __launch_bounds__(256) void to_bf16(
    const float* __restrict__ s0, const float* __restrict__ s1, const float* __restrict__ s2,
    const float* __restrict__ s3, const float* __restrict__ s4, const float* __restrict__ s5,
    const float* __restrict__ s6, u16* __restrict__ Xb, u16* __restrict__ Wb)
{
  size_t c = (size_t)blockIdx.x * 256 + threadIdx.x;
  const float* src;
  u16* dst;
  if (c < 1179648) {
    int seg = (int)(c / 393216);
    size_t off = (c % 393216) * 8;
    src = (seg == 0 ? s0 : seg == 1 ? s1 : s2) + off;
    dst = Xb + (size_t)seg * NEL + off;
  } else {
    size_t c2 = c - 1179648;
    int seg = (int)(c2 / 73728);
    size_t off = (c2 % 73728) * 8;
    src = (seg == 0 ? s3 : seg == 1 ? s4 : seg == 2 ? s5 : s6) + off;
    dst = Wb + (size_t)seg * NWL + off;
  }
  float4 f0 = *(const float4*)(src);
  float4 f1 = *(const float4*)(src + 4);
  u16x8 o;
  o[0] = f2b(f0.x); o[1] = f2b(f0.y); o[2] = f2b(f0.z); o[3] = f2b(f0.w);
  o[4] = f2b(f1.x); o[5] = f2b(f1.y); o[6] = f2b(f1.z); o[7] = f2b(f1.w);
  *(u16x8*)dst = o;
}

// 128x128 tile GEMM, BK=64, gl_lds + xor swizzle. modes: 0 head-major bf16
// (scaled) via LDS-transpose; 1 Vt (d-major, pos32 s); 2 fp32 row-major.
__device__ __forceinline__ void gemm2_core(
    const u16* __restrict__ X, const u16* __restrict__ W, void* __restrict__ Y,
    int m0, int n0, int mode, float scale, u16* As, u16* Bs)
{
  const int tid  = threadIdx.x;
  const int lane = tid & 63, w = tid >> 6;
  const int l15  = lane & 15, quad = lane >> 4;
  const int wm   = (w & 1) * 64, wn = (w >> 1) * 64;

  f32x4 acc[4][4] = {};

  for (int k0 = 0; k0 < DM; k0 += 64) {
    __syncthreads();
#pragma unroll
    for (int i = 0; i < 4; i++) {
      int c = (w * 4 + i) * 64 + lane;
      int row = c >> 3, c8 = c & 7;
      int g8 = c8 ^ (row & 7);
      gl_lds16(X + (size_t)(m0 + row) * DM + k0 + g8 * 8, As + c * 8);
      gl_lds16(W + (size_t)(n0 + row) * DM + k0 + g8 * 8, Bs + c * 8);
    }
    __syncthreads();
#pragma unroll
    for (int dk = 0; dk < 2; dk++) {
      bf16x8 af[4], bf[4];
      int ph = ((dk * 4 + quad) ^ (l15 & 7)) * 8;
#pragma unroll
      for (int t = 0; t < 4; t++) {
        af[t] = *(const bf16x8*)(&As[(wm + t * 16 + l15) * 64 + ph]);
        bf[t] = *(const bf16x8*)(&Bs[(wn + t * 16 + l15) * 64 + ph]);
      }
#pragma unroll
      for (int mt = 0; mt < 4; mt++)
#pragma unroll
        for (int nt = 0; nt < 4; nt++)
          acc[mt][nt] = __builtin_amdgcn_mfma_f32_16x16x32_bf16(af[mt], bf[nt], acc[mt][nt], 0, 0, 0);
    }
  }

  if (mode == 2) {
    float* O = (float*)Y;
#pragma unroll
    for (int mt = 0; mt < 4; mt++) {
      int mg = m0 + wm + mt * 16 + quad * 4;
#pragma unroll
      for (int nt = 0; nt < 4; nt++) {
        int j = n0 + wn + nt * 16 + l15;
#pragma unroll
        for (int r = 0; r < 4; r++)
          O[(size_t)(mg + r) * DM + j] = acc[mt][nt][r];
      }
    }
  } else if (mode == 1) {       // Vt[bh][d][s']
    u16* O = (u16*)Y;
#pragma unroll
    for (int mt = 0; mt < 4; mt++) {
      int mg = m0 + wm + mt * 16 + quad * 4;
      int b = mg >> 11, s = mg & 2047;
      int sp = (s & ~31) | pos32(s & 31);
#pragma unroll
      for (int nt = 0; nt < 4; nt++) {
        int j = n0 + wn + nt * 16 + l15;
        int h = j >> 6, d = j & 63;
        u16x4 o;
#pragma unroll
        for (int r = 0; r < 4; r++) o[r] = f2b(acc[mt][nt][r]);
        *(u16x4*)&O[((size_t)(b * NH + h) * DK + d) * SEQ + sp] = o;
      }
    }
  } else {                      // head-major via LDS transpose, scaled
    u16* O = (u16*)Y;
    u16* T = As;
#pragma unroll
    for (int h2 = 0; h2 < 2; h2++) {
      __syncthreads();
      if ((w & 1) == h2) {
#pragma unroll
        for (int mt = 0; mt < 4; mt++)
#pragma unroll
          for (int nt = 0; nt < 4; nt++)
#pragma unroll
            for (int r = 0; r < 4; r++)
              T[(mt * 16 + quad * 4 + r) * 128 + wn + nt * 16 + l15] = f2b(acc[mt][nt][r] * scale);
      }
      __syncthreads();
#pragma unroll
      for (int i = 0; i < 4; i++) {
        int c = i * 256 + tid;
        int row = c >> 4, ch = c & 15;
        u16x8 val = *(const u16x8*)&T[row * 128 + ch * 8];
        int m = m0 + h2 * 64 + row;
        int j = n0 + ch * 8;
        int hh = j >> 6, d = j & 63;
        int b = m >> 11, s = m & 2047;
        *(u16x8*)&O[((size_t)(b * NH + hh) * SEQ + s) * DK + d] = val;
      }
    }
  }
}

// qkv2: linear grid 576. xcd = L%8 owns m-blocks [xcd*4, xcd*4+4) for ALL
// (n,mat); i%4 = m-offset (fastest), n next, mat slowest -> per-XCD working
// set ~2 MB (one mat's W 1.2MB + 4 X-tiles 0.8MB) fits 4MB L2.
__global__ __launch_bounds__(256) void qkv2(
    const u16* __restrict__ Xb, const u16* __restrict__ Wb,
    u16* __restrict__ Qhm, u16* __restrict__ Khm, u16* __restrict__ Vt)
{
  __shared__ __align__(16) u16 As[128 * 64];
  __shared__ __align__(16) u16 Bs[128 * 64];
  int L = blockIdx.x;
  int xcd = L & 7, i = L >> 3;          // i in [0,72)
  int m = xcd * 4 + (i & 3);            // m-block 0..31
  int rest = i >> 2;                    // 0..17
  int n = rest % 6, mat = rest / 6;
  const u16* X = Xb + (size_t)mat * NEL;
  const u16* W = Wb + (size_t)mat * NWL;
  void* Y = (mat == 0) ? (void*)Qhm : (mat == 1) ? (void*)Khm : (void*)Vt;
  float scale = (mat == 0) ? QSCALE : 1.0f;
  gemm2_core(X, W, Y, m * 128, n * 128, (mat == 2) ? 1 : 0, scale, As, Bs);
}

// bt2: linear grid 192. xcd owns m-blocks [xcd*4,+4) for all n.
__global__ __launch_bounds__(256) void bt2(
    const u16* __restrict__ Ctx, const u16* __restrict__ Wob, float* __restrict__ Y)
{
  __shared__ __align__(16) u16 As[128 * 64];
  __shared__ __align__(16) u16 Bs[128 * 64];
  int L = blockIdx.x;
  int xcd = L & 7, i = L >> 3;          // i in [0,24)
  int m = xcd * 4 + (i & 3);
  int n = i >> 2;                       // 0..5
  gemm2_core(Ctx, Wob, Y, m * 128, n * 128, 2, 1.0f, As, Bs);
}

// attn3: linear grid 768. xcd owns bh in [xcd*3, xcd*3+3): each bh's K/V is
// HBM-fetched once per XCD, L2-served for all 32 q-tiles. bh fastest, qt slow.
// 4 waves; each wave: ALL 64 q, its own 32-key quarter of each 128-key tile.
// Q pre-scaled by QSCALE -> p = exp2(sc). l via ones-A MFMA. 4-wave merge.
__global__ __launch_bounds__(256, 3) void attn3(
    const u16* __restrict__ Qh, const u16* __restrict__ Kh,
    const u16* __restrict__ Vt, u16* __restrict__ ctx)
{
  __shared__ __align__(16) u16 smem[128 * 64 + 64 * 128];  // 32 KB: Ks | Vs; reused as merge buf
  __shared__ float Lsum[4][64];
  u16* Ks = smem;
  u16* Vs = smem + 128 * 64;

  const int tid  = threadIdx.x;
  const int lane = tid & 63, w = tid >> 6;
  const int l15  = lane & 15, quad = lane >> 4;
  int L = blockIdx.x;
  int xcd = L & 7, i = L >> 3;          // i in [0,96)
  const int bh = xcd * 3 + (i % 3);     // 0..23, XCD-local
  const int qt = i / 3;                 // 0..31
  const int b = bh / NH, h = bh % NH;

  const u16* Qb = Qh + (size_t)bh * SEQ * DK;
  const u16* Kb = Kh + (size_t)bh * SEQ * DK;
  const u16* Vb = Vt + (size_t)bh * DK * SEQ;
  const int q0 = qt * 64;

  bf16x8 qf[4][2];   // B[n=q][k=d]
#pragma unroll
  for (int QT = 0; QT < 4; QT++)
#pragma unroll
    for (int dk = 0; dk < 2; dk++)
      qf[QT][dk] = *(const bf16x8*)&Qb[(size_t)(q0 + QT * 16 + l15) * DK + dk * 32 + quad * 8];

  bf16x8 onef;
#pragma unroll
  for (int j = 0; j < 8; j++) onef[j] = (__bf16)1.0f;

  f32x4 oacc[4][4] = {};   // [DT][QT]  O^T: col=q, row=d
  f32x4 lacc[4] = {};      // [QT] row-sums of P (all 4 r equal)

  for (int kt = 0; kt < SEQ; kt += 128) {
    __syncthreads();
#pragma unroll
    for (int i2 = 0; i2 < 4; i2++) {
      int c = (w * 4 + i2) * 64 + lane;   // K: 1024 chunks, row=c>>3
      int row = c >> 3, c8 = c & 7;
      gl_lds16(Kb + (size_t)(kt + row) * DK + (c8 ^ (row & 7)) * 8, Ks + c * 8);
    }
#pragma unroll
    for (int i2 = 0; i2 < 4; i2++) {
      int c = (w * 4 + i2) * 64 + lane;   // V: 1024 chunks, d=c>>4
      int d = c >> 4, c16 = c & 15;
      gl_lds16(Vb + (size_t)d * SEQ + kt + (c16 ^ (d & 15)) * 8, Vs + c * 8);
    }
    __syncthreads();

    // S^T[key][q]: this wave's 32-key quarter, all 64 q
    f32x4 sc[2][4] = {};
#pragma unroll
    for (int MT = 0; MT < 2; MT++) {
      int row = w * 32 + MT * 16 + l15;
#pragma unroll
      for (int dk = 0; dk < 2; dk++) {
        bf16x8 kf = *(const bf16x8*)&Ks[row * 64 + ((dk * 4 + quad) ^ (l15 & 7)) * 8];
#pragma unroll
        for (int QT = 0; QT < 4; QT++)
          sc[MT][QT] = __builtin_amdgcn_mfma_f32_16x16x32_bf16(kf, qf[QT][dk], sc[MT][QT], 0, 0, 0);
      }
    }

    // p = exp2(sc) straight into PV B-frag order; l via ones-MFMA
    bf16x8 pf[4];
#pragma unroll
    for (int QT = 0; QT < 4; QT++) {
#pragma unroll
      for (int j = 0; j < 8; j++)
        pf[QT][j] = (__bf16)__builtin_amdgcn_exp2f(sc[j >> 2][QT][j & 3]);
      lacc[QT] = __builtin_amdgcn_mfma_f32_16x16x32_bf16(onef, pf[QT], lacc[QT], 0, 0, 0);
    }

    // O^T += V^T * P
    int cL = w * 4 + quad;
#pragma unroll
    for (int DT = 0; DT < 4; DT++) {
      int d = DT * 16 + l15;
      bf16x8 vf = *(const bf16x8*)&Vs[d * 128 + (cL ^ (d & 15)) * 8];
#pragma unroll
      for (int QT = 0; QT < 4; QT++)
        oacc[DT][QT] = __builtin_amdgcn_mfma_f32_16x16x32_bf16(vf, pf[QT], oacc[DT][QT], 0, 0, 0);
    }
  }

  __syncthreads();   // tile reads done; smem becomes merge buffer

  if (quad == 0) {
#pragma unroll
    for (int QT = 0; QT < 4; QT++)
      Lsum[w][QT * 16 + l15] = lacc[QT][0];
  }

  // merge partial O across waves: wave w owns DT=w; two rounds of DT pairs.
  float* fb = (float*)smem;
#pragma unroll
  for (int rd = 0; rd < 2; rd++) {
    int p0 = rd * 2, p1 = rd * 2 + 1;
    __syncthreads();
    if (w != p0) {
      int s3 = (w < p0) ? w : w - 1;
#pragma unroll
      for (int QT = 0; QT < 4; QT++)
        *(f32x4*)&fb[(0 * 3 + s3) * 1152 + (QT * 16 + l15) * 18 + quad * 4] = oacc[p0][QT];
    }
    if (w != p1) {
      int s3 = (w < p1) ? w : w - 1;
#pragma unroll
      for (int QT = 0; QT < 4; QT++)
        *(f32x4*)&fb[(1 * 3 + s3) * 1152 + (QT * 16 + l15) * 18 + quad * 4] = oacc[p1][QT];
    }
    __syncthreads();
    if (w == p0) {
#pragma unroll
      for (int s3 = 0; s3 < 3; s3++)
#pragma unroll
        for (int QT = 0; QT < 4; QT++)
          oacc[p0][QT] += *(const f32x4*)&fb[(0 * 3 + s3) * 1152 + (QT * 16 + l15) * 18 + quad * 4];
    }
    if (w == p1) {
#pragma unroll
      for (int s3 = 0; s3 < 3; s3++)
#pragma unroll
        for (int QT = 0; QT < 4; QT++)
          oacc[p1][QT] += *(const f32x4*)&fb[(1 * 3 + s3) * 1152 + (QT * 16 + l15) * 18 + quad * 4];
    }
  }

  // wave w stores its DT=w tile, normalized. Compile-time indices only.
#pragma unroll
  for (int DT = 0; DT < 4; DT++) {
    if (w == DT) {
#pragma unroll
      for (int QT = 0; QT < 4; QT++) {
        int q = QT * 16 + l15;
        float inv = 1.0f / (Lsum[0][q] + Lsum[1][q] + Lsum[2][q] + Lsum[3][q]);
        u16x4 ov;
#pragma unroll
        for (int r = 0; r < 4; r++)
          ov[r] = f2b(oacc[DT][QT][r] * inv);
        *(u16x4*)&ctx[((size_t)(b * SEQ + q0 + q)) * DM + h * DK + DT * 16 + quad * 4] = ov;
      }
    }
  }
}

// ---------------- FALLBACK PATH (round-4, proven) ----------------

__device__ __forceinline__ void stage8(u16* dst, const void* src, size_t elemIdx, int isf32) {
  if (isf32) {
    const float* s = (const float*)src + elemIdx;
    float4 f0 = *(const float4*)(s);
    float4 f1 = *(const float4*)(s + 4);
    u16x8 o;
    o[0] = f2b(f0.x); o[1] = f2b(f0.y); o[2] = f2b(f0.z); o[3] = f2b(f0.w);
    o[4] = f2b(f1.x); o[5] = f2b(f1.y); o[6] = f2b(f1.z); o[7] = f2b(f1.w);
    *(u16x8*)dst = o;
  } else {
    *(float4*)dst = *(const float4*)((const u16*)src + elemIdx);
  }
}

__device__ __forceinline__ void gemm_core_fb(
    const void* __restrict__ X, const void* __restrict__ W, void* __restrict__ Y,
    int m0, int n0, int out_mode, u16* As, u16* Bs, int xf32, int wf32)
{
  const int tid  = threadIdx.x;
  const int lane = tid & 63, w = tid >> 6;
  const int l15  = lane & 15, quad = lane >> 4;
  const int wm   = (w & 1) * 64, wn = (w >> 1) * 64;
  f32x4 acc[4][4] = {};
  for (int k0 = 0; k0 < DM; k0 += 32) {
    __syncthreads();
#pragma unroll
    for (int i = 0; i < 2; i++) {
      int c = i * 256 + tid;
      int row = c >> 2, cc = c & 3;
      stage8(&As[c * 8], X, (size_t)(m0 + row) * DM + k0 + cc * 8, xf32);
      stage8(&Bs[c * 8], W, (size_t)(n0 + row) * DM + k0 + cc * 8, wf32);
    }
    __syncthreads();
    bf16x8 af[4], bf[4];
#pragma unroll
    for (int t = 0; t < 4; t++) {
      af[t] = *(const bf16x8*)(&As[(wm + t * 16 + l15) * 32 + quad * 8]);
      bf[t] = *(const bf16x8*)(&Bs[(wn + t * 16 + l15) * 32 + quad * 8]);
    }
#pragma unroll
    for (int mt = 0; mt < 4; mt++)
#pragma unroll
      for (int nt = 0; nt < 4; nt++)
        acc[mt][nt] = __builtin_amdgcn_mfma_f32_16x16x32_bf16(af[mt], bf[nt], acc[mt][nt], 0, 0, 0);
  }
  if (out_mode == 2) {
    float* O = (float*)Y;
#pragma unroll
    for (int mt = 0; mt < 4; mt++) {
      int mg = m0 + wm + mt * 16 + quad * 4;
#pragma unroll
      for (int nt = 0; nt < 4; nt++) {
        int j = n0 + wn + nt * 16 + l15;
#pragma unroll
        for (int r = 0; r < 4; r++)
          O[(size_t)(mg + r) * DM + j] = acc[mt][nt][r];
      }
    }
  } else {
    u16* O = (u16*)Y;
#pragma unroll
    for (int mt = 0; mt < 4; mt++) {
      int mg = m0 + wm + mt * 16 + quad * 4;
#pragma unroll
      for (int nt = 0; nt < 4; nt++) {
        int j = n0 + wn + nt * 16 + l15;
        int h = j >> 6, d = j & 63;
#pragma unroll
        for (int r = 0; r < 4; r++) {
          int m = mg + r;
          int b = m >> 11, s = m & 2047;
          O[((size_t)(b * NH + h) * SEQ + s) * DK + d] = f2b(acc[mt][nt][r]);
        }
      }
    }
  }
}

__global__ __launch_bounds__(256) void fb_qkv_gemm(
    const float* __restrict__ Xq, const float* __restrict__ Xk, const float* __restrict__ Xv,
    const float* __restrict__ Wq, const float* __restrict__ Wk, const float* __restrict__ Wv,
    u16* __restrict__ Yq, u16* __restrict__ Yk, u16* __restrict__ Yv)
{
  __shared__ __align__(16) u16 As[128 * 32];
  __shared__ __align__(16) u16 Bs[128 * 32];
  int mat = blockIdx.z;
  const float* X = (mat == 0) ? Xq : (mat == 1) ? Xk : Xv;
  const float* W = (mat == 0) ? Wq : (mat == 1) ? Wk : Wv;
  u16*         Y = (mat == 0) ? Yq : (mat == 1) ? Yk : Yv;
  gemm_core_fb(X, W, Y, blockIdx.y * 128, blockIdx.x * 128, 0, As, Bs, 1, 1);
}

__global__ __launch_bounds__(256) void fb_gemm_bt(
    const u16* __restrict__ X, const float* __restrict__ W, float* __restrict__ Y)
{
  __shared__ __align__(16) u16 As[128 * 32];
  __shared__ __align__(16) u16 Bs[128 * 32];
  gemm_core_fb(X, W, Y, blockIdx.y * 128, blockIdx.x * 128, 2, As, Bs, 0, 1);
}

__global__ __launch_bounds__(256) void fb_attn(
    const u16* __restrict__ Qh, const u16* __restrict__ Kh,
    const u16* __restrict__ Vh, u16* __restrict__ ctx)
{
  __shared__ __align__(16) u16 Ks[32 * 88];
  __shared__ __align__(16) u16 Vs[64 * 40];
  __shared__ __align__(16) u16 Ps[4][16 * 32];
  const int tid  = threadIdx.x;
  const int lane = tid & 63, w = tid >> 6;
  const int l15  = lane & 15, quad = lane >> 4;
  const int qt = blockIdx.x, bh = blockIdx.y;
  const int b = bh / NH, h = bh % NH;
  const u16* Qb = Qh + (size_t)bh * SEQ * DK;
  const u16* Kb = Kh + (size_t)bh * SEQ * DK;
  const u16* Vb = Vh + (size_t)bh * SEQ * DK;
  const int q0 = qt * 64 + w * 16;
  bf16x8 qf[2];
#pragma unroll
  for (int kk = 0; kk < 2; kk++)
    qf[kk] = *(const bf16x8*)(&Qb[(size_t)(q0 + l15) * DK + kk * 32 + quad * 8]);
  float m_i[4] = {-INFINITY, -INFINITY, -INFINITY, -INFINITY};
  float l_i[4] = {0.f, 0.f, 0.f, 0.f};
  f32x4 acc[4] = {};
  for (int kt = 0; kt < SEQ; kt += 32) {
    __syncthreads();
    {
      int c = tid;
      int row = c >> 3, c8 = c & 7;
      *(float4*)(&Ks[row * 88 + c8 * 8]) =
          *(const float4*)(&Kb[(size_t)(kt + row) * DK + c8 * 8]);
    }
#pragma unroll
    for (int i = 0; i < 4; i++) {
      int e = i * 256 + tid;
      int k = e >> 5, d2 = e & 31;
      u32 v = *(const u32*)(&Vb[(size_t)(kt + k) * DK + d2 * 2]);
      Vs[(d2 * 2)     * 40 + k] = (u16)(v & 0xffffu);
      Vs[(d2 * 2 + 1) * 40 + k] = (u16)(v >> 16);
    }
    __syncthreads();
    f32x4 sc[2] = {};
#pragma unroll
    for (int ktt = 0; ktt < 2; ktt++)
#pragma unroll
      for (int dk = 0; dk < 2; dk++) {
        bf16x8 kf = *(const bf16x8*)(&Ks[(ktt * 16 + l15) * 88 + dk * 32 + quad * 8]);
        sc[ktt] = __builtin_amdgcn_mfma_f32_16x16x32_bf16(qf[dk], kf, sc[ktt], 0, 0, 0);
      }
    float alph[4];
#pragma unroll
    for (int r = 0; r < 4; r++) {
      float s0 = sc[0][r] * 0.125f;
      float s1 = sc[1][r] * 0.125f;
      float mv = fmaxf(s0, s1);
      mv = fmaxf(mv, __shfl_xor(mv, 1));
      mv = fmaxf(mv, __shfl_xor(mv, 2));
      mv = fmaxf(mv, __shfl_xor(mv, 4));
      mv = fmaxf(mv, __shfl_xor(mv, 8));
      float mnew = fmaxf(m_i[r], mv);
      float a = __expf(m_i[r] - mnew);
      m_i[r] = mnew;
      float p0 = __expf(s0 - mnew);
      float p1 = __expf(s1 - mnew);
      float rs = p0 + p1;
      rs += __shfl_xor(rs, 1);
      rs += __shfl_xor(rs, 2);
      rs += __shfl_xor(rs, 4);
      rs += __shfl_xor(rs, 8);
      l_i[r] = l_i[r] * a + rs;
      alph[r] = a;
      Ps[w][(quad * 4 + r) * 32 +      l15] = f2b(p0);
      Ps[w][(quad * 4 + r) * 32 + 16 + l15] = f2b(p1);
    }
#pragma unroll
    for (int nt = 0; nt < 4; nt++) {
      acc[nt][0] *= alph[0];
      acc[nt][1] *= alph[1];
      acc[nt][2] *= alph[2];
      acc[nt][3] *= alph[3];
    }
    __syncthreads();
    bf16x8 pf = *(const bf16x8*)(&Ps[w][l15 * 32 + quad * 8]);
#pragma unroll
    for (int nt = 0; nt < 4; nt++) {
      bf16x8 vf = *(const bf16x8*)(&Vs[(nt * 16 + l15) * 40 + quad * 8]);
      acc[nt] = __builtin_amdgcn_mfma_f32_16x16x32_bf16(pf, vf, acc[nt], 0, 0, 0);
    }
  }
#pragma unroll
  for (int nt = 0; nt < 4; nt++) {
    int d = nt * 16 + l15;
#pragma unroll
    for (int r = 0; r < 4; r++) {
      int s = q0 + quad * 4 + r;
      float v = acc[nt][r] / l_i[r];
      ctx[((size_t)(b * SEQ + s)) * DM + h * DK + d] = f2b(v);
    }
  }
}

// ---------------- HOST ----------------

extern "C" void kernel_launch(void* const* d_in, const int* in_sizes, int n_in,
                              void* d_out, int out_size, void* d_ws, size_t ws_size,
                              hipStream_t stream) {
  const float* act[3] = {nullptr, nullptr, nullptr};
  const float* wgt[4] = {nullptr, nullptr, nullptr, nullptr};
  int na = 0, nw = 0;
  for (int i = 0; i < n_in && i < 7; i++) {
    if (in_sizes[i] == NEL) { if (na < 3) act[na++] = (const float*)d_in[i]; }
    else                    { if (nw < 4) wgt[nw++] = (const float*)d_in[i]; }
  }
  const float* q  = act[0] ? act[0] : (const float*)d_in[0];
  const float* k  = act[1] ? act[1] : (const float*)d_in[1];
  const float* v  = act[2] ? act[2] : (const float*)d_in[2];
  const float* Wq = wgt[0] ? wgt[0] : (const float*)d_in[3];
  const float* Wk = wgt[1] ? wgt[1] : (const float*)d_in[4];
  const float* Wv = wgt[2] ? wgt[2] : (const float*)d_in[5];
  const float* Wo = wgt[3] ? wgt[3] : (const float*)d_in[6];
  u16* ws = (u16*)d_ws;

  const size_t NE = NEL, NW = NWL;
  const size_t need = (6 * NE + 4 * NW) * 2;   // 42.47 MB

  if (ws_size >= need) {
    u16* Xb  = ws;                 // 3*NE ; later aliased by Ctx
    u16* Wb  = ws + 3 * NE;        // 4*NW
    u16* Qhm = Wb + 4 * NW;
    u16* Khm = Qhm + NE;
    u16* Vt  = Khm + NE;
    u16* Ctx = ws;                 // alias Xb (dead after qkv2)

    to_bf16<<<5760, 256, 0, stream>>>(q, k, v, Wq, Wk, Wv, Wo, Xb, Wb);
    qkv2<<<576, 256, 0, stream>>>(Xb, Wb, Qhm, Khm, Vt);
    attn3<<<768, 256, 0, stream>>>(Qhm, Khm, Vt, Ctx);
    bt2<<<192, 256, 0, stream>>>(Ctx, Wb + 3 * NW, (float*)d_out);
  } else {
    u16* Qhm = ws;
    u16* Khm = ws + NE;
    u16* Vhm = ws + 2 * NE;
    u16* Ctx = ws + 3 * NE;
    fb_qkv_gemm<<<dim3(DM / 128, MTOT / 128, 3), 256, 0, stream>>>(
        q, k, v, Wq, Wk, Wv, Qhm, Khm, Vhm);
    fb_attn<<<dim3(SEQ / 64, NBH), 256, 0, stream>>>(Qhm, Khm, Vhm, Ctx);
    fb_gemm_bt<<<dim3(DM / 128, MTOT / 128), 256, 0, stream>>>(Ctx, Wo, (float*)d_out);
  }
}

// Round 10
// 166.310 us; speedup vs baseline: 2.4473x; 1.1478x over previous
//
#include <hip/hip_runtime.h>
#include <hip/hip_bf16.h>

// MultiHeadAttention B=2,S=2048,D=768,H=12,Dk=64. fp32 in, fp32 out (proven R4).
// FAST: [to_bf16] -> [qkv2 dbuf GEMM] -> [attn4] -> [bt2 dbuf GEMM].
// R10: K-loop restructured for latency hiding (R9 evidence: attn3 invariant at
// ~52us with all throughput counters <25% -> per-iter stage-drain latency bound).
//  - double-buffered LDS, ONE barrier/iter, prefetch issued BEFORE compute so
//    the barrier's vmcnt(0) drain lands after compute (prefetch had ~1000cyc).
//  - attn4: 128q/block, pure q-split (wave owns 32 q, all keys) -> 2x compute
//    per staged byte, wave-local l, NO merge/shuffles (spill-safe epilogue).
// Kept: XCD swizzle (R9: FETCH 58.7->15.7MB), xor-swizzle LDS (conflicts=0),
// Q pre-scaled by 0.125*log2e -> exp2-only softmax, compile-time reg indices.
// FALLBACK (small ws): round-4 proven pipeline.
// Verified MFMA 16x16x32 layouts: A[m=l15][k=quad*8+j], B[n=l15][k=quad*8+j],
// C/D col=l15 row=quad*4+reg.

typedef __bf16 bf16x8 __attribute__((ext_vector_type(8)));
typedef float f32x4 __attribute__((ext_vector_type(4)));
typedef unsigned short u16;
typedef unsigned int u32;
typedef u16 u16x8 __attribute__((ext_vector_type(8)));
typedef u16 u16x4 __attribute__((ext_vector_type(4)));

#define SEQ 2048
#define DM  768
#define NH  12
#define DK  64
#define NBH 24
#define MTOT 4096
#define NEL 3145728   // MTOT*DM
#define NWL 589824    // DM*DM
#define QSCALE 0.18033688f   // 0.125 * log2(e)

#define MFMA16 __builtin_amdgcn_mfma_f32_16x16x32_bf16

__device__ __forceinline__ u16 f2b(float v) {
  __bf16 t = (__bf16)v;
  return __builtin_bit_cast(u16, t);
}

__device__ __forceinline__ void gl_lds16(const u16* g, u16* l) {
  __builtin_amdgcn_global_load_lds(
      (const __attribute__((address_space(1))) void*)g,
      (__attribute__((address_space(3))) void*)l, 16, 0, 0);
}

// key permutation within 32-groups so P's MFMA B-frag register order (k=quad*8+j)
// matches V's stored column order: pos32(MT*16+quad*4+r) = quad*8 + MT*4 + r.
__device__ __forceinline__ int pos32(int k) {
  return (k < 16) ? (((k >> 2) << 3) + (k & 3))
                  : ((((k & 15) >> 2) << 3) + (k & 3) + 4);
}

// ---------------- FAST PATH ----------------

__global__ __launch_bounds__(256) void to_bf16(
    const float* __restrict__ s0, const float* __restrict__ s1, const float* __restrict__ s2,
    const float* __restrict__ s3, const float* __restrict__ s4, const float* __restrict__ s5,
    const float* __restrict__ s6, u16* __restrict__ Xb, u16* __restrict__ Wb)
{
  size_t c = (size_t)blockIdx.x * 256 + threadIdx.x;
  const float* src;
  u16* dst;
  if (c < 1179648) {
    int seg = (int)(c / 393216);
    size_t off = (c % 393216) * 8;
    src = (seg == 0 ? s0 : seg == 1 ? s1 : s2) + off;
    dst = Xb + (size_t)seg * NEL + off;
  } else {
    size_t c2 = c - 1179648;
    int seg = (int)(c2 / 73728);
    size_t off = (c2 % 73728) * 8;
    src = (seg == 0 ? s3 : seg == 1 ? s4 : seg == 2 ? s5 : s6) + off;
    dst = Wb + (size_t)seg * NWL + off;
  }
  float4 f0 = *(const float4*)(src);
  float4 f1 = *(const float4*)(src + 4);
  u16x8 o;
  o[0] = f2b(f0.x); o[1] = f2b(f0.y); o[2] = f2b(f0.z); o[3] = f2b(f0.w);
  o[4] = f2b(f1.x); o[5] = f2b(f1.y); o[6] = f2b(f1.z); o[7] = f2b(f1.w);
  *(u16x8*)dst = o;
}

// ---- dbuf GEMM pieces (128x128 tile, BK=64) ----

__device__ __forceinline__ void g2_stage(
    const u16* __restrict__ X, const u16* __restrict__ W,
    int m0, int n0, int k0, u16* As, u16* Bs, int w, int lane)
{
#pragma unroll
  for (int i = 0; i < 4; i++) {
    int c = (w * 4 + i) * 64 + lane;
    int row = c >> 3, c8 = c & 7;
    int g8 = c8 ^ (row & 7);
    gl_lds16(X + (size_t)(m0 + row) * DM + k0 + g8 * 8, As + c * 8);
    gl_lds16(W + (size_t)(n0 + row) * DM + k0 + g8 * 8, Bs + c * 8);
  }
}

__device__ __forceinline__ void g2_compute(
    const u16* As, const u16* Bs, f32x4 (&acc)[4][4],
    int wm, int wn, int l15, int quad)
{
#pragma unroll
  for (int dk = 0; dk < 2; dk++) {
    bf16x8 af[4], bf[4];
    int ph = ((dk * 4 + quad) ^ (l15 & 7)) * 8;
#pragma unroll
    for (int t = 0; t < 4; t++) {
      af[t] = *(const bf16x8*)(&As[(wm + t * 16 + l15) * 64 + ph]);
      bf[t] = *(const bf16x8*)(&Bs[(wn + t * 16 + l15) * 64 + ph]);
    }
#pragma unroll
    for (int mt = 0; mt < 4; mt++)
#pragma unroll
      for (int nt = 0; nt < 4; nt++)
        acc[mt][nt] = MFMA16(af[mt], bf[nt], acc[mt][nt], 0, 0, 0);
  }
}

// modes: 0 head-major bf16 (scaled) via LDS-transpose; 1 Vt; 2 fp32 row-major.
__device__ __forceinline__ void gemm2_core(
    const u16* __restrict__ X, const u16* __restrict__ W, void* __restrict__ Y,
    int m0, int n0, int mode, float scale,
    u16* AsA, u16* BsA, u16* AsB, u16* BsB)
{
  const int tid  = threadIdx.x;
  const int lane = tid & 63, w = tid >> 6;
  const int l15  = lane & 15, quad = lane >> 4;
  const int wm   = (w & 1) * 64, wn = (w >> 1) * 64;

  f32x4 acc[4][4] = {};

  g2_stage(X, W, m0, n0, 0, AsA, BsA, w, lane);
  __syncthreads();
#pragma unroll
  for (int kp = 0; kp < 12; kp += 2) {
    if (kp + 1 < 12) g2_stage(X, W, m0, n0, (kp + 1) * 64, AsB, BsB, w, lane);
    g2_compute(AsA, BsA, acc, wm, wn, l15, quad);
    __syncthreads();
    if (kp + 2 < 12) g2_stage(X, W, m0, n0, (kp + 2) * 64, AsA, BsA, w, lane);
    g2_compute(AsB, BsB, acc, wm, wn, l15, quad);
    __syncthreads();
  }

  if (mode == 2) {
    float* O = (float*)Y;
#pragma unroll
    for (int mt = 0; mt < 4; mt++) {
      int mg = m0 + wm + mt * 16 + quad * 4;
#pragma unroll
      for (int nt = 0; nt < 4; nt++) {
        int j = n0 + wn + nt * 16 + l15;
#pragma unroll
        for (int r = 0; r < 4; r++)
          O[(size_t)(mg + r) * DM + j] = acc[mt][nt][r];
      }
    }
  } else if (mode == 1) {       // Vt[bh][d][s']
    u16* O = (u16*)Y;
#pragma unroll
    for (int mt = 0; mt < 4; mt++) {
      int mg = m0 + wm + mt * 16 + quad * 4;
      int b = mg >> 11, s = mg & 2047;
      int sp = (s & ~31) | pos32(s & 31);
#pragma unroll
      for (int nt = 0; nt < 4; nt++) {
        int j = n0 + wn + nt * 16 + l15;
        int h = j >> 6, d = j & 63;
        u16x4 o;
#pragma unroll
        for (int r = 0; r < 4; r++) o[r] = f2b(acc[mt][nt][r]);
        *(u16x4*)&O[((size_t)(b * NH + h) * DK + d) * SEQ + sp] = o;
      }
    }
  } else {                      // head-major via LDS transpose (T = AsA), scaled
    u16* O = (u16*)Y;
    u16* T = AsA;
#pragma unroll
    for (int h2 = 0; h2 < 2; h2++) {
      __syncthreads();
      if ((w & 1) == h2) {
#pragma unroll
        for (int mt = 0; mt < 4; mt++)
#pragma unroll
          for (int nt = 0; nt < 4; nt++)
#pragma unroll
            for (int r = 0; r < 4; r++)
              T[(mt * 16 + quad * 4 + r) * 128 + wn + nt * 16 + l15] = f2b(acc[mt][nt][r] * scale);
      }
      __syncthreads();
#pragma unroll
      for (int i = 0; i < 4; i++) {
        int c = i * 256 + tid;
        int row = c >> 4, ch = c & 15;
        u16x8 val = *(const u16x8*)&T[row * 128 + ch * 8];
        int m = m0 + h2 * 64 + row;
        int j = n0 + ch * 8;
        int hh = j >> 6, d = j & 63;
        int b = m >> 11, s = m & 2047;
        *(u16x8*)&O[((size_t)(b * NH + hh) * SEQ + s) * DK + d] = val;
      }
    }
  }
}

// qkv2: linear grid 576, XCD-local m-blocks (R9-proven decode).
__global__ __launch_bounds__(256, 2) void qkv2(
    const u16* __restrict__ Xb, const u16* __restrict__ Wb,
    u16* __restrict__ Qhm, u16* __restrict__ Khm, u16* __restrict__ Vt)
{
  __shared__ __align__(16) u16 AsA[128 * 64];
  __shared__ __align__(16) u16 BsA[128 * 64];
  __shared__ __align__(16) u16 AsB[128 * 64];
  __shared__ __align__(16) u16 BsB[128 * 64];
  int L = blockIdx.x;
  int xcd = L & 7, i = L >> 3;
  int m = xcd * 4 + (i & 3);
  int rest = i >> 2;
  int n = rest % 6, mat = rest / 6;
  const u16* X = Xb + (size_t)mat * NEL;
  const u16* W = Wb + (size_t)mat * NWL;
  void* Y = (mat == 0) ? (void*)Qhm : (mat == 1) ? (void*)Khm : (void*)Vt;
  float scale = (mat == 0) ? QSCALE : 1.0f;
  gemm2_core(X, W, Y, m * 128, n * 128, (mat == 2) ? 1 : 0, scale, AsA, BsA, AsB, BsB);
}

__global__ __launch_bounds__(256, 2) void bt2(
    const u16* __restrict__ Ctx, const u16* __restrict__ Wob, float* __restrict__ Y)
{
  __shared__ __align__(16) u16 AsA[128 * 64];
  __shared__ __align__(16) u16 BsA[128 * 64];
  __shared__ __align__(16) u16 AsB[128 * 64];
  __shared__ __align__(16) u16 BsB[128 * 64];
  int L = blockIdx.x;
  int xcd = L & 7, i = L >> 3;
  int m = xcd * 4 + (i & 3);
  int n = i >> 2;
  gemm2_core(Ctx, Wob, Y, m * 128, n * 128, 2, 1.0f, AsA, BsA, AsB, BsB);
}

// ---- attn4 pieces ----

__device__ __forceinline__ void attn_stage(
    const u16* __restrict__ Kb, const u16* __restrict__ Vb, int kt,
    u16* Ks, u16* Vs, int w, int lane)
{
#pragma unroll
  for (int i = 0; i < 4; i++) {
    int c = (w * 4 + i) * 64 + lane;     // K: 1024 chunks, row=c>>3
    int row = c >> 3, c8 = c & 7;
    gl_lds16(Kb + (size_t)(kt + row) * DK + (c8 ^ (row & 7)) * 8, Ks + c * 8);
  }
#pragma unroll
  for (int i = 0; i < 4; i++) {
    int c = (w * 4 + i) * 64 + lane;     // V: 1024 chunks, d=c>>4
    int d = c >> 4, c16 = c & 15;
    gl_lds16(Vb + (size_t)d * SEQ + kt + (c16 ^ (d & 15)) * 8, Vs + c * 8);
  }
}

// One 128-key tile for this wave's 32 q (QT=2): all keys, two 64-key halves.
__device__ __forceinline__ void attn_compute(
    const u16* Ks, const u16* Vs, const bf16x8 (&qf)[2][2], bf16x8 onef,
    f32x4 (&oacc)[4][2], f32x4 (&lacc)[2], int l15, int quad)
{
#pragma unroll
  for (int kh2 = 0; kh2 < 2; kh2++) {
    f32x4 sc[4][2] = {};
#pragma unroll
    for (int MT = 0; MT < 4; MT++) {
      int row = kh2 * 64 + MT * 16 + l15;
#pragma unroll
      for (int dk = 0; dk < 2; dk++) {
        bf16x8 kf = *(const bf16x8*)&Ks[row * 64 + ((dk * 4 + quad) ^ (l15 & 7)) * 8];
        sc[MT][0] = MFMA16(kf, qf[0][dk], sc[MT][0], 0, 0, 0);
        sc[MT][1] = MFMA16(kf, qf[1][dk], sc[MT][1], 0, 0, 0);
      }
    }
#pragma unroll
    for (int g2 = 0; g2 < 2; g2++) {
      bf16x8 pf[2];
#pragma unroll
      for (int QT = 0; QT < 2; QT++) {
#pragma unroll
        for (int j = 0; j < 8; j++)
          pf[QT][j] = (__bf16)__builtin_amdgcn_exp2f(sc[g2 * 2 + (j >> 2)][QT][j & 3]);
        lacc[QT] = MFMA16(onef, pf[QT], lacc[QT], 0, 0, 0);
      }
      int cL = (kh2 * 2 + g2) * 4 + quad;
#pragma unroll
      for (int DT = 0; DT < 4; DT++) {
        int d = DT * 16 + l15;
        bf16x8 vf = *(const bf16x8*)&Vs[d * 128 + (cL ^ (d & 15)) * 8];
        oacc[DT][0] = MFMA16(vf, pf[0], oacc[DT][0], 0, 0, 0);
        oacc[DT][1] = MFMA16(vf, pf[1], oacc[DT][1], 0, 0, 0);
      }
    }
  }
}

// attn4: linear grid 384 = 8 xcd x (3 bh x 16 qb). 128 q/block; wave w owns
// q [q0+w*32,+32) and processes ALL keys -> wave-local complete O,l (no merge).
// Double-buffered staging, one barrier/iter, prefetch-before-compute.
__global__ __launch_bounds__(256, 2) void attn4(
    const u16* __restrict__ Qh, const u16* __restrict__ Kh,
    const u16* __restrict__ Vt, u16* __restrict__ ctx)
{
  __shared__ __align__(16) u16 KsA[128 * 64];
  __shared__ __align__(16) u16 VsA[64 * 128];
  __shared__ __align__(16) u16 KsB[128 * 64];
  __shared__ __align__(16) u16 VsB[64 * 128];

  const int tid  = threadIdx.x;
  const int lane = tid & 63, w = tid >> 6;
  const int l15  = lane & 15, quad = lane >> 4;
  int L = blockIdx.x;
  int xcd = L & 7, i = L >> 3;          // i in [0,48)
  const int bh = xcd * 3 + (i % 3);
  const int qb = i / 3;                 // 0..15
  const int b = bh / NH, h = bh % NH;

  const u16* Qb = Qh + (size_t)bh * SEQ * DK;
  const u16* Kb = Kh + (size_t)bh * SEQ * DK;
  const u16* Vb = Vt + (size_t)bh * DK * SEQ;
  const int qw = qb * 128 + w * 32;     // this wave's q base

  bf16x8 qf[2][2];
#pragma unroll
  for (int QT = 0; QT < 2; QT++)
#pragma unroll
    for (int dk = 0; dk < 2; dk++)
      qf[QT][dk] = *(const bf16x8*)&Qb[(size_t)(qw + QT * 16 + l15) * DK + dk * 32 + quad * 8];

  bf16x8 onef;
#pragma unroll
  for (int j = 0; j < 8; j++) onef[j] = (__bf16)1.0f;

  f32x4 oacc[4][2] = {};
  f32x4 lacc[2] = {};

  attn_stage(Kb, Vb, 0, KsA, VsA, w, lane);
  __syncthreads();
#pragma unroll
  for (int kp = 0; kp < 16; kp += 2) {
    if (kp + 1 < 16) attn_stage(Kb, Vb, (kp + 1) * 128, KsB, VsB, w, lane);
    attn_compute(KsA, VsA, qf, onef, oacc, lacc, l15, quad);
    __syncthreads();
    if (kp + 2 < 16) attn_stage(Kb, Vb, (kp + 2) * 128, KsA, VsA, w, lane);
    attn_compute(KsB, VsB, qf, onef, oacc, lacc, l15, quad);
    __syncthreads();
  }

  // epilogue: wave-local, compile-time indices, no LDS
#pragma unroll
  for (int QT = 0; QT < 2; QT++) {
    int q = qw + QT * 16 + l15;
    float inv = 1.0f / lacc[QT][0];     // ones-MFMA rows all equal l_q
#pragma unroll
    for (int DT = 0; DT < 4; DT++) {
      u16x4 ov;
#pragma unroll
      for (int r = 0; r < 4; r++)
        ov[r] = f2b(oacc[DT][QT][r] * inv);
      *(u16x4*)&ctx[((size_t)(b * SEQ + q)) * DM + h * DK + DT * 16 + quad * 4] = ov;
    }
  }
}

// ---------------- FALLBACK PATH (round-4, proven) ----------------

__device__ __forceinline__ void stage8(u16* dst, const void* src, size_t elemIdx, int isf32) {
  if (isf32) {
    const float* s = (const float*)src + elemIdx;
    float4 f0 = *(const float4*)(s);
    float4 f1 = *(const float4*)(s + 4);
    u16x8 o;
    o[0] = f2b(f0.x); o[1] = f2b(f0.y); o[2] = f2b(f0.z); o[3] = f2b(f0.w);
    o[4] = f2b(f1.x); o[5] = f2b(f1.y); o[6] = f2b(f1.z); o[7] = f2b(f1.w);
    *(u16x8*)dst = o;
  } else {
    *(float4*)dst = *(const float4*)((const u16*)src + elemIdx);
  }
}

__device__ __forceinline__ void gemm_core_fb(
    const void* __restrict__ X, const void* __restrict__ W, void* __restrict__ Y,
    int m0, int n0, int out_mode, u16* As, u16* Bs, int xf32, int wf32)
{
  const int tid  = threadIdx.x;
  const int lane = tid & 63, w = tid >> 6;
  const int l15  = lane & 15, quad = lane >> 4;
  const int wm   = (w & 1) * 64, wn = (w >> 1) * 64;
  f32x4 acc[4][4] = {};
  for (int k0 = 0; k0 < DM; k0 += 32) {
    __syncthreads();
#pragma unroll
    for (int i = 0; i < 2; i++) {
      int c = i * 256 + tid;
      int row = c >> 2, cc = c & 3;
      stage8(&As[c * 8], X, (size_t)(m0 + row) * DM + k0 + cc * 8, xf32);
      stage8(&Bs[c * 8], W, (size_t)(n0 + row) * DM + k0 + cc * 8, wf32);
    }
    __syncthreads();
    bf16x8 af[4], bf[4];
#pragma unroll
    for (int t = 0; t < 4; t++) {
      af[t] = *(const bf16x8*)(&As[(wm + t * 16 + l15) * 32 + quad * 8]);
      bf[t] = *(const bf16x8*)(&Bs[(wn + t * 16 + l15) * 32 + quad * 8]);
    }
#pragma unroll
    for (int mt = 0; mt < 4; mt++)
#pragma unroll
      for (int nt = 0; nt < 4; nt++)
        acc[mt][nt] = MFMA16(af[mt], bf[nt], acc[mt][nt], 0, 0, 0);
  }
  if (out_mode == 2) {
    float* O = (float*)Y;
#pragma unroll
    for (int mt = 0; mt < 4; mt++) {
      int mg = m0 + wm + mt * 16 + quad * 4;
#pragma unroll
      for (int nt = 0; nt < 4; nt++) {
        int j = n0 + wn + nt * 16 + l15;
#pragma unroll
        for (int r = 0; r < 4; r++)
          O[(size_t)(mg + r) * DM + j] = acc[mt][nt][r];
      }
    }
  } else {
    u16* O = (u16*)Y;
#pragma unroll
    for (int mt = 0; mt < 4; mt++) {
      int mg = m0 + wm + mt * 16 + quad * 4;
#pragma unroll
      for (int nt = 0; nt < 4; nt++) {
        int j = n0 + wn + nt * 16 + l15;
        int h = j >> 6, d = j & 63;
#pragma unroll
        for (int r = 0; r < 4; r++) {
          int m = mg + r;
          int b = m >> 11, s = m & 2047;
          O[((size_t)(b * NH + h) * SEQ + s) * DK + d] = f2b(acc[mt][nt][r]);
        }
      }
    }
  }
}

__global__ __launch_bounds__(256) void fb_qkv_gemm(
    const float* __restrict__ Xq, const float* __restrict__ Xk, const float* __restrict__ Xv,
    const float* __restrict__ Wq, const float* __restrict__ Wk, const float* __restrict__ Wv,
    u16* __restrict__ Yq, u16* __restrict__ Yk, u16* __restrict__ Yv)
{
  __shared__ __align__(16) u16 As[128 * 32];
  __shared__ __align__(16) u16 Bs[128 * 32];
  int mat = blockIdx.z;
  const float* X = (mat == 0) ? Xq : (mat == 1) ? Xk : Xv;
  const float* W = (mat == 0) ? Wq : (mat == 1) ? Wk : Wv;
  u16*         Y = (mat == 0) ? Yq : (mat == 1) ? Yk : Yv;
  gemm_core_fb(X, W, Y, blockIdx.y * 128, blockIdx.x * 128, 0, As, Bs, 1, 1);
}

__global__ __launch_bounds__(256) void fb_gemm_bt(
    const u16* __restrict__ X, const float* __restrict__ W, float* __restrict__ Y)
{
  __shared__ __align__(16) u16 As[128 * 32];
  __shared__ __align__(16) u16 Bs[128 * 32];
  gemm_core_fb(X, W, Y, blockIdx.y * 128, blockIdx.x * 128, 2, As, Bs, 0, 1);
}

__global__ __launch_bounds__(256) void fb_attn(
    const u16* __restrict__ Qh, const u16* __restrict__ Kh,
    const u16* __restrict__ Vh, u16* __restrict__ ctx)
{
  __shared__ __align__(16) u16 Ks[32 * 88];
  __shared__ __align__(16) u16 Vs[64 * 40];
  __shared__ __align__(16) u16 Ps[4][16 * 32];
  const int tid  = threadIdx.x;
  const int lane = tid & 63, w = tid >> 6;
  const int l15  = lane & 15, quad = lane >> 4;
  const int qt = blockIdx.x, bh = blockIdx.y;
  const int b = bh / NH, h = bh % NH;
  const u16* Qb = Qh + (size_t)bh * SEQ * DK;
  const u16* Kb = Kh + (size_t)bh * SEQ * DK;
  const u16* Vb = Vh + (size_t)bh * SEQ * DK;
  const int q0 = qt * 64 + w * 16;
  bf16x8 qf[2];
#pragma unroll
  for (int kk = 0; kk < 2; kk++)
    qf[kk] = *(const bf16x8*)(&Qb[(size_t)(q0 + l15) * DK + kk * 32 + quad * 8]);
  float m_i[4] = {-INFINITY, -INFINITY, -INFINITY, -INFINITY};
  float l_i[4] = {0.f, 0.f, 0.f, 0.f};
  f32x4 acc[4] = {};
  for (int kt = 0; kt < SEQ; kt += 32) {
    __syncthreads();
    {
      int c = tid;
      int row = c >> 3, c8 = c & 7;
      *(float4*)(&Ks[row * 88 + c8 * 8]) =
          *(const float4*)(&Kb[(size_t)(kt + row) * DK + c8 * 8]);
    }
#pragma unroll
    for (int i = 0; i < 4; i++) {
      int e = i * 256 + tid;
      int k = e >> 5, d2 = e & 31;
      u32 v = *(const u32*)(&Vb[(size_t)(kt + k) * DK + d2 * 2]);
      Vs[(d2 * 2)     * 40 + k] = (u16)(v & 0xffffu);
      Vs[(d2 * 2 + 1) * 40 + k] = (u16)(v >> 16);
    }
    __syncthreads();
    f32x4 sc[2] = {};
#pragma unroll
    for (int ktt = 0; ktt < 2; ktt++)
#pragma unroll
      for (int dk = 0; dk < 2; dk++) {
        bf16x8 kf = *(const bf16x8*)(&Ks[(ktt * 16 + l15) * 88 + dk * 32 + quad * 8]);
        sc[ktt] = MFMA16(qf[dk], kf, sc[ktt], 0, 0, 0);
      }
    float alph[4];
#pragma unroll
    for (int r = 0; r < 4; r++) {
      float s0 = sc[0][r] * 0.125f;
      float s1 = sc[1][r] * 0.125f;
      float mv = fmaxf(s0, s1);
      mv = fmaxf(mv, __shfl_xor(mv, 1));
      mv = fmaxf(mv, __shfl_xor(mv, 2));
      mv = fmaxf(mv, __shfl_xor(mv, 4));
      mv = fmaxf(mv, __shfl_xor(mv, 8));
      float mnew = fmaxf(m_i[r], mv);
      float a = __expf(m_i[r] - mnew);
      m_i[r] = mnew;
      float p0 = __expf(s0 - mnew);
      float p1 = __expf(s1 - mnew);
      float rs = p0 + p1;
      rs += __shfl_xor(rs, 1);
      rs += __shfl_xor(rs, 2);
      rs += __shfl_xor(rs, 4);
      rs += __shfl_xor(rs, 8);
      l_i[r] = l_i[r] * a + rs;
      alph[r] = a;
      Ps[w][(quad * 4 + r) * 32 +      l15] = f2b(p0);
      Ps[w][(quad * 4 + r) * 32 + 16 + l15] = f2b(p1);
    }
#pragma unroll
    for (int nt = 0; nt < 4; nt++) {
      acc[nt][0] *= alph[0];
      acc[nt][1] *= alph[1];
      acc[nt][2] *= alph[2];
      acc[nt][3] *= alph[3];
    }
    __syncthreads();
    bf16x8 pf = *(const bf16x8*)(&Ps[w][l15 * 32 + quad * 8]);
#pragma unroll
    for (int nt = 0; nt < 4; nt++) {
      bf16x8 vf = *(const bf16x8*)(&Vs[(nt * 16 + l15) * 40 + quad * 8]);
      acc[nt] = MFMA16(pf, vf, acc[nt], 0, 0, 0);
    }
  }
#pragma unroll
  for (int nt = 0; nt < 4; nt++) {
    int d = nt * 16 + l15;
#pragma unroll
    for (int r = 0; r < 4; r++) {
      int s = q0 + quad * 4 + r;
      float v = acc[nt][r] / l_i[r];
      ctx[((size_t)(b * SEQ + s)) * DM + h * DK + d] = f2b(v);
    }
  }
}

// ---------------- HOST ----------------

extern "C" void kernel_launch(void* const* d_in, const int* in_sizes, int n_in,
                              void* d_out, int out_size, void* d_ws, size_t ws_size,
                              hipStream_t stream) {
  const float* act[3] = {nullptr, nullptr, nullptr};
  const float* wgt[4] = {nullptr, nullptr, nullptr, nullptr};
  int na = 0, nw = 0;
  for (int i = 0; i < n_in && i < 7; i++) {
    if (in_sizes[i] == NEL) { if (na < 3) act[na++] = (const float*)d_in[i]; }
    else                    { if (nw < 4) wgt[nw++] = (const float*)d_in[i]; }
  }
  const float* q  = act[0] ? act[0] : (const float*)d_in[0];
  const float* k  = act[1] ? act[1] : (const float*)d_in[1];
  const float* v  = act[2] ? act[2] : (const float*)d_in[2];
  const float* Wq = wgt[0] ? wgt[0] : (const float*)d_in[3];
  const float* Wk = wgt[1] ? wgt[1] : (const float*)d_in[4];
  const float* Wv = wgt[2] ? wgt[2] : (const float*)d_in[5];
  const float* Wo = wgt[3] ? wgt[3] : (const float*)d_in[6];
  u16* ws = (u16*)d_ws;

  const size_t NE = NEL, NW = NWL;
  const size_t need = (6 * NE + 4 * NW) * 2;   // 42.47 MB

  if (ws_size >= need) {
    u16* Xb  = ws;                 // 3*NE ; later aliased by Ctx
    u16* Wb  = ws + 3 * NE;        // 4*NW
    u16* Qhm = Wb + 4 * NW;
    u16* Khm = Qhm + NE;
    u16* Vt  = Khm + NE;
    u16* Ctx = ws;                 // alias Xb (dead after qkv2)

    to_bf16<<<5760, 256, 0, stream>>>(q, k, v, Wq, Wk, Wv, Wo, Xb, Wb);
    qkv2<<<576, 256, 0, stream>>>(Xb, Wb, Qhm, Khm, Vt);
    attn4<<<384, 256, 0, stream>>>(Qhm, Khm, Vt, Ctx);
    bt2<<<192, 256, 0, stream>>>(Ctx, Wb + 3 * NW, (float*)d_out);
  } else {
    u16* Qhm = ws;
    u16* Khm = ws + NE;
    u16* Vhm = ws + 2 * NE;
    u16* Ctx = ws + 3 * NE;
    fb_qkv_gemm<<<dim3(DM / 128, MTOT / 128, 3), 256, 0, stream>>>(
        q, k, v, Wq, Wk, Wv, Qhm, Khm, Vhm);
    fb_attn<<<dim3(SEQ / 64, NBH), 256, 0, stream>>>(Qhm, Khm, Vhm, Ctx);
    fb_gemm_bt<<<dim3(DM / 128, MTOT / 128), 256, 0, stream>>>(Ctx, Wo, (float*)d_out);
  }
}